// Round 10
// baseline (300.025 us; speedup 1.0000x reference)
//
#include <hip/hip_runtime.h>
#include <math.h>

#define HWSZ 16384

typedef __attribute__((ext_vector_type(8))) short bf16x8;
typedef __attribute__((ext_vector_type(4))) float f32x4;
typedef unsigned short u16;

union U4 { uint4 v; u16 s[8]; };
union U2 { uint2 v; u16 s[4]; };

__device__ __forceinline__ float gelu_f(float v) {
    return 0.5f * v * (1.0f + erff(v * 0.70710678118654752f));
}
__device__ __forceinline__ float splus_f(float v) {
    return (v > 20.f) ? v : log1pf(expf(v));
}
__device__ __forceinline__ u16 f2bf(float f) {
    union { float f; unsigned u; } v; v.f = f;
    unsigned r = (v.u + 0x7FFF + ((v.u >> 16) & 1)) >> 16;
    return (u16)r;
}
__device__ __forceinline__ unsigned pk2(float a, float b) {
    return (unsigned)f2bf(a) | ((unsigned)f2bf(b) << 16);
}
__device__ __forceinline__ float bf2f(u16 s) {
    union { unsigned u; float f; } v; v.u = ((unsigned)s) << 16; return v.f;
}

// ---------------- Kernel 0: weight pre-conversion to bf16 (one-time) ----------------
__global__ __launch_bounds__(256) void k_prep(
    const float* __restrict__ w1, const float* __restrict__ qw,
    const float* __restrict__ kw, const float* __restrict__ vw,
    const float* __restrict__ ow, const float* __restrict__ fw1s,
    const float* __restrict__ fw2s, u16* __restrict__ wout)
{
    int id = blockIdx.x*256 + threadIdx.x;
    float v;
    if (id < 8192) {
        v = w1[id];
    } else if (id < 20480) {
        int t = id - 8192; int m = t >> 12;
        int i = t & 4095; int o = i >> 6, c = i & 63;
        const float* src = (m==0) ? qw : ((m==1) ? kw : vw);
        v = src[c*64 + o];
        if (m == 1) v *= 0.25f;
    } else if (id < 24576) {
        int i = id - 20480; int c = i >> 6, k = i & 63;
        v = ow[k*64 + c];
    } else if (id < 40960) {
        int i = id - 24576; int o = i >> 6, k = i & 63;
        v = fw1s[k*256 + o];
    } else {
        int i = id - 40960; int jc = i >> 12; int r = i & 4095;
        int c = r >> 6, k2 = r & 63;
        v = fw2s[(jc*64 + k2)*64 + c];
    }
    wout[id] = f2bf(v);
}

// ---------------- Kernel 1: fused gate + QKV + RoPE + dt (MFMA, 64 pos/block) ----------------
// Phase 1 (gate): hid = relu([y||th]@w1^T); wts = softmax(hid@w2^T); fused = y*w0+th*w1 -> Af (LDS)
// Phase 2 (qkv): Q=x@qw, K/V=fused@{kw,vw} + RoPE + dt. Gate output never touches global.
__global__ __launch_bounds__(256) void k_fuse_qkv(
    const float* __restrict__ x, const float* __restrict__ y,
    const float* __restrict__ th,
    const u16* __restrict__ wfuse, const float* __restrict__ b1,
    const float* __restrict__ w2, const float* __restrict__ b2,
    const u16* __restrict__ bq, const float* __restrict__ qb,
    const u16* __restrict__ bk, const float* __restrict__ kb,
    const u16* __restrict__ bv, const float* __restrict__ vb,
    const float* __restrict__ dtw, const float* __restrict__ dtb,
    const float* __restrict__ alog,
    u16* __restrict__ qr, u16* __restrict__ kr, u16* __restrict__ v5,
    float* __restrict__ da, float* __restrict__ db)
{
    // phase-aliased LDS: gate {Fsh[64][136], Wt[64][136]} / qkv {Ax[64][72], Bq/Bk/Bv[64][72]}
    __shared__ u16 SL[18432];
    __shared__ u16 AfL[4608];    // fused bf16 [p][c], persistent across phases
    u16* Fsh = SL;               // [64][136]: c2 0..63 = y, 64..127 = th
    u16* Wt  = SL + 8704;        // [64][136]
    u16* Ax  = SL;               // [64][72]
    u16* Bq  = SL + 4608;
    u16* Bk  = SL + 9216;
    u16* Bv  = SL + 13824;
    u16* Af  = AfL;              // [64][72]
    int tid = threadIdx.x, bid = blockIdx.x;
    int pbase = bid*64;
    int b = pbase >> 14, p0 = pbase & 16383;
    int lane = tid & 63, wv = tid >> 6;
    int quad = lane >> 4, lm = lane & 15;
    int M0 = wv*16;
    f32x4 z = {0.f,0.f,0.f,0.f};

    // ---- phase 1: stage y/th + gate weights ----
    for (int vi = tid; vi < 512; vi += 256) {
        int cp = vi >> 4, p4 = (vi & 15)*4;
        int c0 = cp*2;
        float4 a = *(const float4*)&y [((size_t)(b*64+c0  ))*HWSZ + p0 + p4];
        float4 c = *(const float4*)&y [((size_t)(b*64+c0+1))*HWSZ + p0 + p4];
        *(unsigned*)&Fsh[(p4+0)*136 + c0] = pk2(a.x, c.x);
        *(unsigned*)&Fsh[(p4+1)*136 + c0] = pk2(a.y, c.y);
        *(unsigned*)&Fsh[(p4+2)*136 + c0] = pk2(a.z, c.z);
        *(unsigned*)&Fsh[(p4+3)*136 + c0] = pk2(a.w, c.w);
        float4 e = *(const float4*)&th[((size_t)(b*64+c0  ))*HWSZ + p0 + p4];
        float4 f = *(const float4*)&th[((size_t)(b*64+c0+1))*HWSZ + p0 + p4];
        *(unsigned*)&Fsh[(p4+0)*136 + 64 + c0] = pk2(e.x, f.x);
        *(unsigned*)&Fsh[(p4+1)*136 + 64 + c0] = pk2(e.y, f.y);
        *(unsigned*)&Fsh[(p4+2)*136 + 64 + c0] = pk2(e.z, f.z);
        *(unsigned*)&Fsh[(p4+3)*136 + 64 + c0] = pk2(e.w, f.w);
    }
    for (int vi = tid; vi < 1024; vi += 256) {
        int o = vi >> 4, s8 = (vi & 15)*8;
        *(uint4*)&Wt[o*136 + s8] = *(const uint4*)&wfuse[o*128 + s8];
    }
    __syncthreads();
    // ---- gate MFMA: hid[64 pos][64 o], K=128 ----
    {
        f32x4 acc[4];
        #pragma unroll
        for (int nt = 0; nt < 4; ++nt) acc[nt] = z;
        #pragma unroll
        for (int ks = 0; ks < 4; ++ks) {
            bf16x8 aF = *(bf16x8*)&Fsh[(M0+lm)*136 + ks*32 + quad*8];
            #pragma unroll
            for (int nt = 0; nt < 4; ++nt) {
                bf16x8 bW = *(bf16x8*)&Wt[(nt*16+lm)*136 + ks*32 + quad*8];
                acc[nt] = __builtin_amdgcn_mfma_f32_16x16x32_bf16(aF, bW, acc[nt], 0,0,0);
            }
        }
        float b1v[4], w2av[4], w2bv[4];
        #pragma unroll
        for (int nt = 0; nt < 4; ++nt) {
            int o = nt*16 + lm;
            b1v[nt] = b1[o]; w2av[nt] = w2[o]; w2bv[nt] = w2[64+o];
        }
        float bias2a = b2[0], bias2b = b2[1];
        #pragma unroll
        for (int r = 0; r < 4; ++r) {
            int p = M0 + quad*4 + r;
            float l0 = 0.f, l1 = 0.f;
            #pragma unroll
            for (int nt = 0; nt < 4; ++nt) {
                float h = fmaxf(acc[nt][r] + b1v[nt], 0.f);
                l0 += h * w2av[nt];
                l1 += h * w2bv[nt];
            }
            l0 += __shfl_xor(l0,1,64); l0 += __shfl_xor(l0,2,64);
            l0 += __shfl_xor(l0,4,64); l0 += __shfl_xor(l0,8,64);
            l1 += __shfl_xor(l1,1,64); l1 += __shfl_xor(l1,2,64);
            l1 += __shfl_xor(l1,4,64); l1 += __shfl_xor(l1,8,64);
            l0 += bias2a; l1 += bias2b;
            float m = fmaxf(l0, l1);
            float e0 = __expf(l0 - m), e1 = __expf(l1 - m);
            float inv = 1.f/(e0 + e1);
            float wa = e0*inv, wb = e1*inv;
            U2 yv, tv;
            yv.v = *(uint2*)&Fsh[p*136 + lm*4];
            tv.v = *(uint2*)&Fsh[p*136 + 64 + lm*4];
            unsigned o0 = pk2(bf2f(yv.s[0])*wa + bf2f(tv.s[0])*wb,
                              bf2f(yv.s[1])*wa + bf2f(tv.s[1])*wb);
            unsigned o1 = pk2(bf2f(yv.s[2])*wa + bf2f(tv.s[2])*wb,
                              bf2f(yv.s[3])*wa + bf2f(tv.s[3])*wb);
            *(uint2*)&Af[p*72 + lm*4] = make_uint2(o0, o1);
        }
    }
    __syncthreads();   // Af complete; Fsh/Wt dead -> reuse as Ax/Bq/Bk/Bv

    // ---- phase 2: stage x + qkv weights ----
    for (int vi = tid; vi < 512; vi += 256) {
        int cp = vi >> 4, p4 = (vi & 15)*4;
        int c0 = cp*2;
        float4 a = *(const float4*)&x[((size_t)(b*64+c0  ))*HWSZ + p0 + p4];
        float4 c = *(const float4*)&x[((size_t)(b*64+c0+1))*HWSZ + p0 + p4];
        *(unsigned*)&Ax[(p4+0)*72 + c0] = pk2(a.x, c.x);
        *(unsigned*)&Ax[(p4+1)*72 + c0] = pk2(a.y, c.y);
        *(unsigned*)&Ax[(p4+2)*72 + c0] = pk2(a.z, c.z);
        *(unsigned*)&Ax[(p4+3)*72 + c0] = pk2(a.w, c.w);
    }
    for (int vi = tid; vi < 1536; vi += 256) {
        int m = vi >> 9;
        int i = vi & 511;
        int o = i >> 3, s8 = (i & 7)*8;
        const u16* src = (m==0) ? bq : ((m==1) ? bk : bv);
        u16* dst = (m==0) ? Bq : ((m==1) ? Bk : Bv);
        *(uint4*)&dst[o*72 + s8] = *(const uint4*)&src[o*64 + s8];
    }
    __syncthreads();
    f32x4 accQ[4], accK[4], accV[4];
    #pragma unroll
    for (int nt = 0; nt < 4; ++nt) { accQ[nt]=z; accK[nt]=z; accV[nt]=z; }
    #pragma unroll
    for (int ks = 0; ks < 2; ++ks) {
        bf16x8 aX = *(bf16x8*)&Ax[(M0+lm)*72 + ks*32 + quad*8];
        bf16x8 aF = *(bf16x8*)&Af[(M0+lm)*72 + ks*32 + quad*8];
        #pragma unroll
        for (int nt = 0; nt < 4; ++nt) {
            bf16x8 bQ = *(bf16x8*)&Bq[(nt*16+lm)*72 + ks*32 + quad*8];
            bf16x8 bK = *(bf16x8*)&Bk[(nt*16+lm)*72 + ks*32 + quad*8];
            bf16x8 bV = *(bf16x8*)&Bv[(nt*16+lm)*72 + ks*32 + quad*8];
            accQ[nt] = __builtin_amdgcn_mfma_f32_16x16x32_bf16(aX, bQ, accQ[nt], 0,0,0);
            accK[nt] = __builtin_amdgcn_mfma_f32_16x16x32_bf16(aF, bK, accK[nt], 0,0,0);
            accV[nt] = __builtin_amdgcn_mfma_f32_16x16x32_bf16(aF, bV, accV[nt], 0,0,0);
        }
    }
    // ---- dt / da / db (from Ax) ----
    {
        float dtw_[32];
        #pragma unroll
        for (int i = 0; i < 32; ++i) dtw_[i] = dtw[i];
        int p = tid >> 2, n = tid & 3;
        U4 a, c;
        a.v = *(const uint4*)&Ax[p*72 + n*16];
        c.v = *(const uint4*)&Ax[p*72 + n*16 + 8];
        float dt0 = 0.f, dt1 = 0.f;
        #pragma unroll
        for (int d = 0; d < 8; ++d) {
            float xv = bf2f(a.s[d]);
            dt0 += xv*dtw_[2*d];
            dt1 += xv*dtw_[2*d+1];
        }
        #pragma unroll
        for (int d = 0; d < 8; ++d) {
            float xv = bf2f(c.s[d]);
            dt0 += xv*dtw_[16+2*d];
            dt1 += xv*dtw_[16+2*d+1];
        }
        float A = -expf(alog[n]);
        float bb = dtb[n];
        int P = p0 + p;
        int h = P >> 7, w = P & 127;
        da[((b*128+h)*4+n)*128 + w] = splus_f(dt0+bb)*A;
        db[((b*128+w)*4+n)*128 + h] = splus_f(dt1+bb)*A;
    }
    // ---- epilogue: bias, RoPE, pack bf16, store ----
    float qbv[4], kbv[4], vbv[4];
    #pragma unroll
    for (int nt = 0; nt < 4; ++nt) {
        qbv[nt] = qb[nt*16+lm]; kbv[nt] = kb[nt*16+lm]*0.25f; vbv[nt] = vb[nt*16+lm];
    }
    bool evn = !(lm & 1);
    float ang = exp2f(-1.89824462565f * (float)(lm >> 1));
    int bb4 = b*4;
    #pragma unroll
    for (int r = 0; r < 4; ++r) {
        int P = p0 + M0 + quad*4 + r;
        float sn_, cs_;
        sincosf((float)P * ang, &sn_, &cs_);
        #pragma unroll
        for (int nt = 0; nt < 4; ++nt) {
            float vq = accQ[nt][r] + qbv[nt];
            float pq = __shfl_xor(vq, 1, 64);
            float rq = evn ? vq*cs_ - pq*sn_ : vq*cs_ + pq*sn_;
            unsigned uq = f2bf(rq);
            unsigned upq = (unsigned)__shfl_xor((int)uq, 1, 64);
            float vk = accK[nt][r] + kbv[nt];
            float pk = __shfl_xor(vk, 1, 64);
            float rk = evn ? vk*cs_ - pk*sn_ : vk*cs_ + pk*sn_;
            unsigned uk = f2bf(rk);
            unsigned upk = (unsigned)__shfl_xor((int)uk, 1, 64);
            unsigned uv = f2bf(accV[nt][r] + vbv[nt]);
            unsigned upv = (unsigned)__shfl_xor((int)uv, 1, 64);
            if (evn) {
                size_t off = ((size_t)(bb4+nt)*HWSZ + P)*16 + lm;
                *(unsigned*)&qr[off] = (uq & 0xffff) | (upq << 16);
                *(unsigned*)&kr[off] = (uk & 0xffff) | (upk << 16);
                *(unsigned*)&v5[off] = (uv & 0xffff) | (upv << 16);
            }
        }
    }
}

// ---------------- Kernel 3: LePE depthwise 5x5 conv (v5 bf16 in, bf16 out) ----------------
#define LROW 328
__global__ __launch_bounds__(256) void k_lepe(
    const u16* __restrict__ v5, const float* __restrict__ lw,
    const float* __restrict__ lb, u16* __restrict__ lepe)
{
    __shared__ float sv[36*LROW];
    __shared__ float swt[400];
    int tid = threadIdx.x, bid = blockIdx.x;
    int tw = bid & 7, th_ = (bid >> 3) & 3, n = (bid >> 5) & 3, b = bid >> 7;
    int bn = b*4 + n;
    int h0 = th_*32, w0 = tw*16;
    for (int i = tid; i < 400; i += 256) {
        int tap = i >> 4, d = i & 15;
        swt[i] = lw[tap*64 + n*16 + d];
    }
    const u16* vb = v5 + (size_t)bn*HWSZ*16;
    for (int vi = tid; vi < 1440; vi += 256) {
        int cell = vi >> 1, half = vi & 1;
        int hh = cell/20, ww = cell - hh*20;
        int h = h0 - 2 + hh, w = w0 - 2 + ww;
        U4 val; val.v = make_uint4(0,0,0,0);
        if (h >= 0 && h < 128 && w >= 0 && w < 128)
            val.v = *(const uint4*)&vb[((size_t)(h*128+w))*16 + half*8];
        float* dst = &sv[hh*LROW + ww*16 + half*8];
        #pragma unroll
        for (int u = 0; u < 8; ++u) dst[u] = bf2f(val.s[u]);
    }
    __syncthreads();
    int df = (tid & 3)*4;
    int s  = tid >> 2;
    int ph = s >> 1;
    int pw = (s & 1)*8;
    float4 bv = *(const float4*)&lb[n*16 + df];
    float acc[8][4];
    #pragma unroll
    for (int ow = 0; ow < 8; ++ow) {
        acc[ow][0] = bv.x; acc[ow][1] = bv.y; acc[ow][2] = bv.z; acc[ow][3] = bv.w;
    }
    #pragma unroll
    for (int ky = 0; ky < 5; ++ky) {
        float wgt[5][4];
        #pragma unroll
        for (int kx = 0; kx < 5; ++kx) {
            float4 wv = *(const float4*)&swt[(ky*5+kx)*16 + df];
            wgt[kx][0]=wv.x; wgt[kx][1]=wv.y; wgt[kx][2]=wv.z; wgt[kx][3]=wv.w;
        }
        float dat[13][4];
        #pragma unroll
        for (int c = 0; c < 13; ++c) {
            float4 dv = *(const float4*)&sv[(ph+ky)*LROW + (pw+c)*16 + df];
            dat[c][0]=dv.x; dat[c][1]=dv.y; dat[c][2]=dv.z; dat[c][3]=dv.w;
        }
        #pragma unroll
        for (int ow = 0; ow < 8; ++ow)
            #pragma unroll
            for (int kx = 0; kx < 5; ++kx)
                #pragma unroll
                for (int u = 0; u < 4; ++u)
                    acc[ow][u] += dat[ow+kx][u]*wgt[kx][u];
    }
    u16* ob = lepe + ((size_t)bn*HWSZ + (size_t)(h0+ph)*128 + w0+pw)*16 + df;
    #pragma unroll
    for (int ow = 0; ow < 8; ++ow)
        *(uint2*)&ob[ow*16] = make_uint2(pk2(acc[ow][0],acc[ow][1]), pk2(acc[ow][2],acc[ow][3]));
}

// ---------------- Kernel 4: row attention pass 1 -> v_w ----------------
// Q/K fragments loaded direct from global (no LDS staging; quad>=2 holds K-pad zeros).
__global__ __launch_bounds__(256) void k_attn_w1(
    const u16* __restrict__ qr, const u16* __restrict__ kr,
    const u16* __restrict__ v5, const float* __restrict__ dacs,
    u16* __restrict__ vwb)
{
    __shared__ u16 Vt[16*136], Ps[128*136];
    __shared__ float csr[128];
    int tid = threadIdx.x, bid = blockIdx.x;
    int h = bid & 127, n = (bid >> 7) & 3, b = bid >> 9;
    size_t rowoff = ((size_t)((b*4+n)*128 + h)) * 2048;
    {   // V^T
        int jp = tid >> 2, q4 = tid & 3;
        U2 a, c;
        a.v = *(const uint2*)&v5[rowoff + (2*jp)*16 + q4*4];
        c.v = *(const uint2*)&v5[rowoff + (2*jp+1)*16 + q4*4];
        #pragma unroll
        for (int u = 0; u < 4; ++u)
            *(unsigned*)&Vt[(q4*4+u)*136 + 2*jp] = (unsigned)a.s[u] | ((unsigned)c.s[u] << 16);
    }
    if (tid < 128) csr[tid] = dacs[((b*128+h)*4+n)*128 + tid];
    __syncthreads();
    if (tid < 64) {
        float2 e = *(float2*)&csr[tid*2];
        float s = e.x + e.y;
        #pragma unroll
        for (int d = 1; d < 64; d <<= 1) {
            float t = __shfl_up(s, d, 64);
            if (tid >= d) s += t;
        }
        csr[tid*2]   = s - e.y;
        csr[tid*2+1] = s;
    }
    __syncthreads();
    int lane = tid & 63, wv = tid >> 6;
    int quad = lane >> 4, lm = lane & 15;
    int r0 = wv*32, r1 = wv*32 + 16;
    bf16x8 z8 = {0,0,0,0,0,0,0,0};
    bf16x8 aQ0 = z8, aQ1 = z8;
    if (quad < 2) {
        aQ0 = *(const bf16x8*)&qr[rowoff + (size_t)(r0+lm)*16 + quad*8];
        aQ1 = *(const bf16x8*)&qr[rowoff + (size_t)(r1+lm)*16 + quad*8];
    }
    float csj[8], csi0[4], csi1[4];
    #pragma unroll
    for (int jt = 0; jt < 8; ++jt) csj[jt] = csr[jt*16+lm];
    #pragma unroll
    for (int r = 0; r < 4; ++r) { csi0[r] = csr[r0+quad*4+r]; csi1[r] = csr[r1+quad*4+r]; }
    float ls0[4]={0,0,0,0}, ls1[4]={0,0,0,0};
    f32x4 z = {0.f,0.f,0.f,0.f};
    #pragma unroll
    for (int jt = 0; jt < 8; ++jt) {
        bf16x8 bK = z8;
        if (quad < 2) bK = *(const bf16x8*)&kr[rowoff + (size_t)(jt*16+lm)*16 + quad*8];
        f32x4 s0 = __builtin_amdgcn_mfma_f32_16x16x32_bf16(aQ0, bK, z, 0,0,0);
        f32x4 s1 = __builtin_amdgcn_mfma_f32_16x16x32_bf16(aQ1, bK, z, 0,0,0);
        #pragma unroll
        for (int r = 0; r < 4; ++r) {
            float e0 = __expf(s0[r] - fabsf(csi0[r]-csj[jt])); ls0[r] += e0;
            float e1 = __expf(s1[r] - fabsf(csi1[r]-csj[jt])); ls1[r] += e1;
            Ps[(r0+quad*4+r)*136 + jt*16+lm] = f2bf(e0);
            Ps[(r1+quad*4+r)*136 + jt*16+lm] = f2bf(e1);
        }
    }
    float inv0[4], inv1[4];
    #pragma unroll
    for (int r = 0; r < 4; ++r) {
        #pragma unroll
        for (int m = 1; m < 16; m <<= 1) {
            ls0[r] += __shfl_xor(ls0[r], m, 64);
            ls1[r] += __shfl_xor(ls1[r], m, 64);
        }
        inv0[r] = 1.f/ls0[r]; inv1[r] = 1.f/ls1[r];
    }
    __syncthreads();
    f32x4 acc0 = z, acc1 = z;
    #pragma unroll
    for (int c = 0; c < 4; ++c) {
        bf16x8 bV  = *(bf16x8*)&Vt[lm*136 + c*32 + quad*8];
        bf16x8 aP0 = *(bf16x8*)&Ps[(r0+lm)*136 + c*32 + quad*8];
        bf16x8 aP1 = *(bf16x8*)&Ps[(r1+lm)*136 + c*32 + quad*8];
        acc0 = __builtin_amdgcn_mfma_f32_16x16x32_bf16(aP0, bV, acc0, 0,0,0);
        acc1 = __builtin_amdgcn_mfma_f32_16x16x32_bf16(aP1, bV, acc1, 0,0,0);
    }
    bool evn = !(lm & 1);
    #pragma unroll
    for (int r = 0; r < 4; ++r) {
        int i0 = r0+quad*4+r, i1 = r1+quad*4+r;
        unsigned u0 = f2bf(acc0[r]*inv0[r]);
        unsigned u1 = f2bf(acc1[r]*inv1[r]);
        unsigned up0 = (unsigned)__shfl_xor((int)u0, 1, 64);
        unsigned up1 = (unsigned)__shfl_xor((int)u1, 1, 64);
        if (evn) {
            *(unsigned*)&vwb[rowoff + (size_t)i0*16 + lm] = (u0 & 0xffff) | (up0 << 16);
            *(unsigned*)&vwb[rowoff + (size_t)i1*16 + lm] = (u1 & 0xffff) | (up1 << 16);
        }
    }
}

// ---------------- Kernel 5: column attention -> v_h, out1 ----------------
__global__ __launch_bounds__(256) void k_attn_h(
    const u16* __restrict__ qr, const u16* __restrict__ kr,
    const u16* __restrict__ v5, const u16* __restrict__ vwb,
    const float* __restrict__ dbcs,
    u16* __restrict__ vhb, u16* __restrict__ o1b)
{
    __shared__ u16 Vt[16*136], Wt[16*136], Ps[128*136];
    __shared__ float csr[128];
    int tid = threadIdx.x, bid = blockIdx.x;
    int w = bid & 127, n = (bid >> 7) & 3, b = bid >> 9;
    int bn = b*4 + n;
    size_t base = ((size_t)bn*16384 + w)*16;
    {
        int jp = tid >> 2, q4 = tid & 3;
        U2 a, c, e, f;
        a.v = *(const uint2*)&v5 [base + (size_t)(2*jp)*2048 + q4*4];
        c.v = *(const uint2*)&v5 [base + (size_t)(2*jp+1)*2048 + q4*4];
        e.v = *(const uint2*)&vwb[base + (size_t)(2*jp)*2048 + q4*4];
        f.v = *(const uint2*)&vwb[base + (size_t)(2*jp+1)*2048 + q4*4];
        #pragma unroll
        for (int u = 0; u < 4; ++u) {
            *(unsigned*)&Vt[(q4*4+u)*136 + 2*jp] = (unsigned)a.s[u] | ((unsigned)c.s[u] << 16);
            *(unsigned*)&Wt[(q4*4+u)*136 + 2*jp] = (unsigned)e.s[u] | ((unsigned)f.s[u] << 16);
        }
    }
    if (tid < 128) csr[tid] = dbcs[((b*128+w)*4+n)*128 + tid];
    __syncthreads();
    if (tid < 64) {
        float2 e = *(float2*)&csr[tid*2];
        float s = e.x + e.y;
        #pragma unroll
        for (int d = 1; d < 64; d <<= 1) {
            float t = __shfl_up(s, d, 64);
            if (tid >= d) s += t;
        }
        csr[tid*2]   = s - e.y;
        csr[tid*2+1] = s;
    }
    __syncthreads();
    int lane = tid & 63, wv = tid >> 6;
    int quad = lane >> 4, lm = lane & 15;
    int r0 = wv*32, r1 = wv*32 + 16;
    bf16x8 z8 = {0,0,0,0,0,0,0,0};
    bf16x8 aQ0 = z8, aQ1 = z8;
    if (quad < 2) {
        aQ0 = *(const bf16x8*)&qr[base + (size_t)(r0+lm)*2048 + quad*8];
        aQ1 = *(const bf16x8*)&qr[base + (size_t)(r1+lm)*2048 + quad*8];
    }
    float csj[8], csi0[4], csi1[4];
    #pragma unroll
    for (int jt = 0; jt < 8; ++jt) csj[jt] = csr[jt*16+lm];
    #pragma unroll
    for (int r = 0; r < 4; ++r) { csi0[r] = csr[r0+quad*4+r]; csi1[r] = csr[r1+quad*4+r]; }
    float ls0[4]={0,0,0,0}, ls1[4]={0,0,0,0};
    f32x4 z = {0.f,0.f,0.f,0.f};
    #pragma unroll
    for (int jt = 0; jt < 8; ++jt) {
        bf16x8 bK = z8;
        if (quad < 2) bK = *(const bf16x8*)&kr[base + (size_t)(jt*16+lm)*2048 + quad*8];
        f32x4 s0 = __builtin_amdgcn_mfma_f32_16x16x32_bf16(aQ0, bK, z, 0,0,0);
        f32x4 s1 = __builtin_amdgcn_mfma_f32_16x16x32_bf16(aQ1, bK, z, 0,0,0);
        #pragma unroll
        for (int r = 0; r < 4; ++r) {
            float e0 = __expf(s0[r] - fabsf(csi0[r]-csj[jt])); ls0[r] += e0;
            float e1 = __expf(s1[r] - fabsf(csi1[r]-csj[jt])); ls1[r] += e1;
            Ps[(r0+quad*4+r)*136 + jt*16+lm] = f2bf(e0);
            Ps[(r1+quad*4+r)*136 + jt*16+lm] = f2bf(e1);
        }
    }
    float inv0[4], inv1[4];
    #pragma unroll
    for (int r = 0; r < 4; ++r) {
        #pragma unroll
        for (int m = 1; m < 16; m <<= 1) {
            ls0[r] += __shfl_xor(ls0[r], m, 64);
            ls1[r] += __shfl_xor(ls1[r], m, 64);
        }
        inv0[r] = 1.f/ls0[r]; inv1[r] = 1.f/ls1[r];
    }
    __syncthreads();
    f32x4 aV0 = z, aV1 = z, aW0 = z, aW1 = z;
    #pragma unroll
    for (int c = 0; c < 4; ++c) {
        bf16x8 bV  = *(bf16x8*)&Vt[lm*136 + c*32 + quad*8];
        bf16x8 bW  = *(bf16x8*)&Wt[lm*136 + c*32 + quad*8];
        bf16x8 aP0 = *(bf16x8*)&Ps[(r0+lm)*136 + c*32 + quad*8];
        bf16x8 aP1 = *(bf16x8*)&Ps[(r1+lm)*136 + c*32 + quad*8];
        aV0 = __builtin_amdgcn_mfma_f32_16x16x32_bf16(aP0, bV, aV0, 0,0,0);
        aV1 = __builtin_amdgcn_mfma_f32_16x16x32_bf16(aP1, bV, aV1, 0,0,0);
        aW0 = __builtin_amdgcn_mfma_f32_16x16x32_bf16(aP0, bW, aW0, 0,0,0);
        aW1 = __builtin_amdgcn_mfma_f32_16x16x32_bf16(aP1, bW, aW1, 0,0,0);
    }
    size_t obase = ((size_t)bn*16384 + (size_t)w*128)*16;   // [w][h][d]
    bool evn = !(lm & 1);
    #pragma unroll
    for (int r = 0; r < 4; ++r) {
        int i0 = r0+quad*4+r, i1 = r1+quad*4+r;
        float v0 = inv0[r], v1 = inv1[r];
        unsigned a0 = f2bf(aV0[r]*v0), a1 = f2bf(aV1[r]*v1);
        unsigned b0 = f2bf(aW0[r]*v0), b1 = f2bf(aW1[r]*v1);
        unsigned ap0 = (unsigned)__shfl_xor((int)a0,1,64), ap1 = (unsigned)__shfl_xor((int)a1,1,64);
        unsigned bp0 = (unsigned)__shfl_xor((int)b0,1,64), bp1 = (unsigned)__shfl_xor((int)b1,1,64);
        if (evn) {
            *(unsigned*)&vhb[obase + (size_t)i0*16 + lm] = (a0 & 0xffff) | (ap0 << 16);
            *(unsigned*)&vhb[obase + (size_t)i1*16 + lm] = (a1 & 0xffff) | (ap1 << 16);
            *(unsigned*)&o1b[obase + (size_t)i0*16 + lm] = (b0 & 0xffff) | (bp0 << 16);
            *(unsigned*)&o1b[obase + (size_t)i1*16 + lm] = (b1 & 0xffff) | (bp1 << 16);
        }
    }
}

// ---------------- Kernel 6: row attention pass 2 -> out2, combine + lepe ----------------
__global__ __launch_bounds__(256) void k_attn_w2(
    const u16* __restrict__ qr, const u16* __restrict__ kr,
    const u16* __restrict__ vhb, const u16* __restrict__ o1b,
    const float* __restrict__ dacs, const u16* __restrict__ lepe,
    u16* __restrict__ attn)
{
    __shared__ u16 Vt[16*136], Ps[128*136];
    __shared__ float csr[128];
    int tid = threadIdx.x, bid = blockIdx.x;
    int h = bid & 127, n = (bid >> 7) & 3, b = bid >> 9;
    int bn = b*4 + n;
    size_t rowoff = ((size_t)(bn*128 + h)) * 2048;
    size_t vbase  = (size_t)bn*262144 + (size_t)h*16;
    {
        int jp = tid >> 2, q4 = tid & 3;
        U2 a, c;
        a.v = *(const uint2*)&vhb[vbase + (size_t)(2*jp)*2048 + q4*4];
        c.v = *(const uint2*)&vhb[vbase + (size_t)(2*jp+1)*2048 + q4*4];
        #pragma unroll
        for (int u = 0; u < 4; ++u)
            *(unsigned*)&Vt[(q4*4+u)*136 + 2*jp] = (unsigned)a.s[u] | ((unsigned)c.s[u] << 16);
    }
    if (tid < 128) csr[tid] = dacs[((b*128+h)*4+n)*128 + tid];
    __syncthreads();
    if (tid < 64) {
        float2 e = *(float2*)&csr[tid*2];
        float s = e.x + e.y;
        #pragma unroll
        for (int d = 1; d < 64; d <<= 1) {
            float t = __shfl_up(s, d, 64);
            if (tid >= d) s += t;
        }
        csr[tid*2]   = s - e.y;
        csr[tid*2+1] = s;
    }
    __syncthreads();
    int lane = tid & 63, wv = tid >> 6;
    int quad = lane >> 4, lm = lane & 15;
    int r0 = wv*32, r1 = wv*32 + 16;
    bf16x8 z8 = {0,0,0,0,0,0,0,0};
    bf16x8 aQ0 = z8, aQ1 = z8;
    if (quad < 2) {
        aQ0 = *(const bf16x8*)&qr[rowoff + (size_t)(r0+lm)*16 + quad*8];
        aQ1 = *(const bf16x8*)&qr[rowoff + (size_t)(r1+lm)*16 + quad*8];
    }
    float csj[8], csi0[4], csi1[4];
    #pragma unroll
    for (int jt = 0; jt < 8; ++jt) csj[jt] = csr[jt*16+lm];
    #pragma unroll
    for (int r = 0; r < 4; ++r) { csi0[r] = csr[r0+quad*4+r]; csi1[r] = csr[r1+quad*4+r]; }
    float ls0[4]={0,0,0,0}, ls1[4]={0,0,0,0};
    f32x4 z = {0.f,0.f,0.f,0.f};
    #pragma unroll
    for (int jt = 0; jt < 8; ++jt) {
        bf16x8 bK = z8;
        if (quad < 2) bK = *(const bf16x8*)&kr[rowoff + (size_t)(jt*16+lm)*16 + quad*8];
        f32x4 s0 = __builtin_amdgcn_mfma_f32_16x16x32_bf16(aQ0, bK, z, 0,0,0);
        f32x4 s1 = __builtin_amdgcn_mfma_f32_16x16x32_bf16(aQ1, bK, z, 0,0,0);
        #pragma unroll
        for (int r = 0; r < 4; ++r) {
            float e0 = __expf(s0[r] - fabsf(csi0[r]-csj[jt])); ls0[r] += e0;
            float e1 = __expf(s1[r] - fabsf(csi1[r]-csj[jt])); ls1[r] += e1;
            Ps[(r0+quad*4+r)*136 + jt*16+lm] = f2bf(e0);
            Ps[(r1+quad*4+r)*136 + jt*16+lm] = f2bf(e1);
        }
    }
    float inv0[4], inv1[4];
    #pragma unroll
    for (int r = 0; r < 4; ++r) {
        #pragma unroll
        for (int m = 1; m < 16; m <<= 1) {
            ls0[r] += __shfl_xor(ls0[r], m, 64);
            ls1[r] += __shfl_xor(ls1[r], m, 64);
        }
        inv0[r] = 1.f/ls0[r]; inv1[r] = 1.f/ls1[r];
    }
    __syncthreads();
    f32x4 acc0 = z, acc1 = z;
    #pragma unroll
    for (int c = 0; c < 4; ++c) {
        bf16x8 bV  = *(bf16x8*)&Vt[lm*136 + c*32 + quad*8];
        bf16x8 aP0 = *(bf16x8*)&Ps[(r0+lm)*136 + c*32 + quad*8];
        bf16x8 aP1 = *(bf16x8*)&Ps[(r1+lm)*136 + c*32 + quad*8];
        acc0 = __builtin_amdgcn_mfma_f32_16x16x32_bf16(aP0, bV, acc0, 0,0,0);
        acc1 = __builtin_amdgcn_mfma_f32_16x16x32_bf16(aP1, bV, acc1, 0,0,0);
    }
    size_t lpb = (size_t)bn*262144 + (size_t)h*2048;
    size_t oab = (size_t)b*1048576 + (size_t)h*8192 + n*16;
    bool evn = !(lm & 1);
    #pragma unroll
    for (int r = 0; r < 4; ++r) {
        int i0 = r0+quad*4+r, i1 = r1+quad*4+r;
        float o2a = acc0[r]*inv0[r];
        float o2b = acc1[r]*inv1[r];
        float o1a = bf2f(o1b[vbase + (size_t)i0*2048 + lm]);
        float o1c = bf2f(o1b[vbase + (size_t)i1*2048 + lm]);
        float la  = bf2f(lepe[lpb + (size_t)i0*16 + lm]);
        float lc  = bf2f(lepe[lpb + (size_t)i1*16 + lm]);
        unsigned ua = f2bf(0.5f*(o1a + o2a) + la);
        unsigned uc = f2bf(0.5f*(o1c + o2b) + lc);
        unsigned upa = (unsigned)__shfl_xor((int)ua,1,64);
        unsigned upc = (unsigned)__shfl_xor((int)uc,1,64);
        if (evn) {
            *(unsigned*)&attn[oab + (size_t)i0*64 + lm] = (ua & 0xffff) | (upa << 16);
            *(unsigned*)&attn[oab + (size_t)i1*64 + lm] = (uc & 0xffff) | (upc << 16);
        }
    }
}

// ---------------- Kernel 7: out-proj + residual + LN1 (MFMA, 64 pos/block) ----------------
__global__ __launch_bounds__(256) void k_proj_ln(
    const u16* __restrict__ attn, const float* __restrict__ x,
    const u16* __restrict__ bo, const float* __restrict__ ob,
    const float* __restrict__ g1, const float* __restrict__ b1,
    u16* __restrict__ t1)
{
    __shared__ u16 As[64*72];
    __shared__ u16 Bs[64*72];
    __shared__ float XT[64*68];
    int tid = threadIdx.x, bid = blockIdx.x;
    int pbase = bid*64;
    int b = pbase >> 14, p0 = pbase & 16383;
    for (int vi = tid; vi < 512; vi += 256) {
        int p = vi >> 3, s8 = (vi & 7)*8;
        *(uint4*)&As[p*72 + s8] = *(const uint4*)&attn[((size_t)(pbase+p))*64 + s8];
    }
    for (int vi = tid; vi < 512; vi += 256) {
        int c = vi >> 3, s8 = (vi & 7)*8;
        *(uint4*)&Bs[c*72 + s8] = *(const uint4*)&bo[c*64 + s8];
    }
    for (int vi = tid; vi < 1024; vi += 256) {
        int c = vi >> 4, p4 = (vi & 15)*4;
        *(float4*)&XT[c*68 + p4] = *(const float4*)&x[((size_t)(b*64+c))*HWSZ + p0 + p4];
    }
    __syncthreads();
    int lane = tid & 63, wv = tid >> 6;
    int quad = lane >> 4, lm = lane & 15;
    int M0 = wv*16;
    float xv[4][4], obv[4], g1v[4], b1v[4];
    #pragma unroll
    for (int nt = 0; nt < 4; ++nt) {
        int c = nt*16 + lm;
        obv[nt] = ob[c]; g1v[nt] = g1[c]; b1v[nt] = b1[c];
        #pragma unroll
        for (int r = 0; r < 4; ++r)
            xv[nt][r] = XT[c*68 + M0 + quad*4 + r];
    }
    f32x4 z = {0.f,0.f,0.f,0.f};
    f32x4 acc[4];
    #pragma unroll
    for (int nt = 0; nt < 4; ++nt) acc[nt] = z;
    #pragma unroll
    for (int ks = 0; ks < 2; ++ks) {
        bf16x8 aF = *(bf16x8*)&As[(M0+lm)*72 + ks*32 + quad*8];
        #pragma unroll
        for (int nt = 0; nt < 4; ++nt) {
            bf16x8 bF = *(bf16x8*)&Bs[(nt*16+lm)*72 + ks*32 + quad*8];
            acc[nt] = __builtin_amdgcn_mfma_f32_16x16x32_bf16(aF, bF, acc[nt], 0,0,0);
        }
    }
    float val[4][4], res[4][4];
    #pragma unroll
    for (int r = 0; r < 4; ++r) {
        float s = 0.f;
        #pragma unroll
        for (int nt = 0; nt < 4; ++nt) {
            val[nt][r] = acc[nt][r] + obv[nt] + xv[nt][r];
            s += val[nt][r];
        }
        s += __shfl_xor(s, 1, 64); s += __shfl_xor(s, 2, 64);
        s += __shfl_xor(s, 4, 64); s += __shfl_xor(s, 8, 64);
        float mean = s*(1.f/64.f);
        float vv = 0.f;
        #pragma unroll
        for (int nt = 0; nt < 4; ++nt) {
            float d = val[nt][r] - mean;
            vv += d*d;
        }
        vv += __shfl_xor(vv, 1, 64); vv += __shfl_xor(vv, 2, 64);
        vv += __shfl_xor(vv, 4, 64); vv += __shfl_xor(vv, 8, 64);
        float rs = rsqrtf(vv*(1.f/64.f) + 1e-5f);
        #pragma unroll
        for (int nt = 0; nt < 4; ++nt)
            res[nt][r] = (val[nt][r] - mean)*rs*g1v[nt] + b1v[nt];
    }
    __syncthreads();
    float* outT = XT;   // [p][68]
    #pragma unroll
    for (int r = 0; r < 4; ++r)
        #pragma unroll
        for (int nt = 0; nt < 4; ++nt)
            outT[(M0+quad*4+r)*68 + nt*16 + lm] = res[nt][r];
    __syncthreads();
    for (int vi = tid; vi < 512; vi += 256) {
        int p = vi >> 3, s8 = (vi & 7)*8;
        float4 f0 = *(const float4*)&outT[p*68 + s8];
        float4 f1 = *(const float4*)&outT[p*68 + s8 + 4];
        uint4 o = make_uint4(pk2(f0.x,f0.y), pk2(f0.z,f0.w), pk2(f1.x,f1.y), pk2(f1.z,f1.w));
        *(uint4*)&t1[((size_t)(pbase+p))*64 + s8] = o;
    }
}

// ---------------- Kernel 8: fused FFN (MFMA, 64 pos/block) + residual + LN2 + transpose ----------------
__global__ __launch_bounds__(256) void k_ffn(
    const u16* __restrict__ t1, const u16* __restrict__ fw1,
    const float* __restrict__ b1f, const u16* __restrict__ fw2,
    const float* __restrict__ b2f, const float* __restrict__ g2,
    const float* __restrict__ bb2, float* __restrict__ outp)
{
    __shared__ u16 SL[18432];
    __shared__ float sb1[256];
    __shared__ float sb2[64], sg[64], sbb[64];
    u16* At1 = SL;
    u16* W1b = SL + 4608;
    u16* W2b = SL + 9216;
    u16* Hid = SL + 13824;
    int tid = threadIdx.x, bid = blockIdx.x;
    int pbase = bid*64;
    int b = pbase >> 14, p0 = pbase & 16383;
    for (int vi = tid; vi < 512; vi += 256) {
        int p = vi >> 3, s8 = (vi & 7)*8;
        *(uint4*)&At1[p*72 + s8] = *(const uint4*)&t1[((size_t)(pbase+p))*64 + s8];
    }
    if (tid < 256) sb1[tid] = b1f[tid];
    if (tid < 64) { sb2[tid] = b2f[tid]; sg[tid] = g2[tid]; sbb[tid] = bb2[tid]; }
    int lane = tid & 63, wv = tid >> 6;
    int quad = lane >> 4, lm = lane & 15;
    int M0 = wv*16;
    f32x4 z = {0.f,0.f,0.f,0.f};
    f32x4 acc2[4];
    #pragma unroll
    for (int nt = 0; nt < 4; ++nt) acc2[nt] = z;
    for (int jc = 0; jc < 4; ++jc) {
        __syncthreads();
        for (int vi = tid; vi < 1024; vi += 256) {
            int m = vi >> 9, i = vi & 511;
            int o = i >> 3, s8 = (i & 7)*8;
            if (m == 0) *(uint4*)&W1b[o*72 + s8] = *(const uint4*)&fw1[(jc*64+o)*64 + s8];
            else        *(uint4*)&W2b[o*72 + s8] = *(const uint4*)&fw2[jc*4096 + o*64 + s8];
        }
        __syncthreads();
        f32x4 h[4];
        #pragma unroll
        for (int nt = 0; nt < 4; ++nt) h[nt] = z;
        #pragma unroll
        for (int ks = 0; ks < 2; ++ks) {
            bf16x8 aF = *(bf16x8*)&At1[(M0+lm)*72 + ks*32 + quad*8];
            #pragma unroll
            for (int nt = 0; nt < 4; ++nt) {
                bf16x8 bF = *(bf16x8*)&W1b[(nt*16+lm)*72 + ks*32 + quad*8];
                h[nt] = __builtin_amdgcn_mfma_f32_16x16x32_bf16(aF, bF, h[nt], 0,0,0);
            }
        }
        #pragma unroll
        for (int nt = 0; nt < 4; ++nt) {
            float bb = sb1[jc*64 + nt*16 + lm];
            #pragma unroll
            for (int r = 0; r < 4; ++r) {
                float hv = gelu_f(h[nt][r] + bb);
                unsigned u = (unsigned)f2bf(hv);
                unsigned up = (unsigned)__shfl_xor((int)u, 1, 64);
                if (!(lm & 1))
                    *(unsigned*)&Hid[(M0+quad*4+r)*72 + nt*16 + lm] = (u & 0xffff) | (up << 16);
            }
        }
        #pragma unroll
        for (int ks = 0; ks < 2; ++ks) {
            bf16x8 aH = *(bf16x8*)&Hid[(M0+lm)*72 + ks*32 + quad*8];
            #pragma unroll
            for (int nt = 0; nt < 4; ++nt) {
                bf16x8 bF = *(bf16x8*)&W2b[(nt*16+lm)*72 + ks*32 + quad*8];
                acc2[nt] = __builtin_amdgcn_mfma_f32_16x16x32_bf16(aH, bF, acc2[nt], 0,0,0);
            }
        }
    }
    float val[4][4], res[4][4];
    float sb2v[4], sgv[4], sbbv[4];
    #pragma unroll
    for (int nt = 0; nt < 4; ++nt) {
        int c = nt*16 + lm;
        sb2v[nt] = sb2[c]; sgv[nt] = sg[c]; sbbv[nt] = sbb[c];
    }
    #pragma unroll
    for (int r = 0; r < 4; ++r) {
        int pos = M0 + quad*4 + r;
        float s = 0.f;
        #pragma unroll
        for (int nt = 0; nt < 4; ++nt) {
            float tv = bf2f(At1[pos*72 + nt*16 + lm]);
            val[nt][r] = acc2[nt][r] + sb2v[nt] + tv;
            s += val[nt][r];
        }
        s += __shfl_xor(s, 1, 64); s += __shfl_xor(s, 2, 64);
        s += __shfl_xor(s, 4, 64); s += __shfl_xor(s, 8, 64);
        float mean = s*(1.f/64.f);
        float vv = 0.f;
        #pragma unroll
        for (int nt = 0; nt < 4; ++nt) {
            float d = val[nt][r] - mean;
            vv += d*d;
        }
        vv += __shfl_xor(vv, 1, 64); vv += __shfl_xor(vv, 2, 64);
        vv += __shfl_xor(vv, 4, 64); vv += __shfl_xor(vv, 8, 64);
        float rs = rsqrtf(vv*(1.f/64.f) + 1e-5f);
        #pragma unroll
        for (int nt = 0; nt < 4; ++nt)
            res[nt][r] = (val[nt][r] - mean)*rs*sgv[nt] + sbbv[nt];
    }
    __syncthreads();
    float* outT = (float*)SL;   // [c][68]
    #pragma unroll
    for (int r = 0; r < 4; ++r)
        #pragma unroll
        for (int nt = 0; nt < 4; ++nt)
            outT[(nt*16+lm)*68 + M0 + quad*4 + r] = res[nt][r];
    __syncthreads();
    for (int vi = tid; vi < 1024; vi += 256) {
        int c = vi >> 4, p4 = (vi & 15)*4;
        *(float4*)&outp[((size_t)(b*64+c))*HWSZ + p0 + p4] = *(const float4*)&outT[c*68 + p4];
    }
}

extern "C" void kernel_launch(void* const* d_in, const int* in_sizes, int n_in,
                              void* d_out, int out_size, void* d_ws, size_t ws_size,
                              hipStream_t stream) {
    const float* x      = (const float*)d_in[0];
    const float* y      = (const float*)d_in[1];
    const float* th     = (const float*)d_in[2];
    const float* dw1_w  = (const float*)d_in[3];
    const float* dw1_b  = (const float*)d_in[4];
    const float* dw2_w  = (const float*)d_in[5];
    const float* dw2_b  = (const float*)d_in[6];
    const float* qw     = (const float*)d_in[7];
    const float* qb     = (const float*)d_in[8];
    const float* kw     = (const float*)d_in[9];
    const float* kb     = (const float*)d_in[10];
    const float* vw     = (const float*)d_in[11];
    const float* vb     = (const float*)d_in[12];
    const float* lepe_w = (const float*)d_in[13];
    const float* lepe_b = (const float*)d_in[14];
    const float* dt_w   = (const float*)d_in[15];
    const float* dt_bias= (const float*)d_in[16];
    const float* A_log  = (const float*)d_in[17];
    const float* ow     = (const float*)d_in[18];
    const float* ob     = (const float*)d_in[19];
    const float* n1_g   = (const float*)d_in[20];
    const float* n1_b   = (const float*)d_in[21];
    const float* ffn_w1 = (const float*)d_in[22];
    const float* ffn_b1 = (const float*)d_in[23];
    const float* ffn_w2 = (const float*)d_in[24];
    const float* ffn_b2 = (const float*)d_in[25];
    const float* n2_g   = (const float*)d_in[26];
    const float* n2_b   = (const float*)d_in[27];
    float* out = (float*)d_out;

    const size_t SZ = 4194304;
    float* ws    = (float*)d_ws;
    u16* vwbuf = (u16*)(ws + 0*SZ);    // v_w (vwb) written by attn_w1
    u16* qrb   = (u16*)(ws + 1*SZ);
    u16* krb   = (u16*)(ws + 2*SZ);
    u16* v5b   = (u16*)(ws + 3*SZ);
    u16* lepeb = (u16*)(ws + 4*SZ);
    u16* vhb   = (u16*)(ws + 5*SZ);
    u16* o1b   = (u16*)(ws + 6*SZ);
    u16* attnb = (u16*)(ws + 7*SZ);
    u16* t1b   = (u16*)(ws + 8*SZ);
    float* dacs  = ws + 9*SZ;
    float* dbcs  = ws + 9*SZ + 262144;
    u16* wall  = (u16*)(ws + 9*SZ + 524288);
    u16* wfuse = wall;
    u16* bq    = wall + 8192;
    u16* bk    = wall + 12288;
    u16* bv    = wall + 16384;
    u16* bo    = wall + 20480;
    u16* fw1   = wall + 24576;
    u16* fw2   = wall + 40960;

    k_prep<<<224, 256, 0, stream>>>(dw1_w, qw, kw, vw, ow, ffn_w1, ffn_w2, wall);
    k_fuse_qkv<<<1024, 256, 0, stream>>>(x, y, th, wfuse, dw1_b, dw2_w, dw2_b,
                                         bq, qb, bk, kb, bv, vb,
                                         dt_w, dt_bias, A_log, qrb, krb, v5b, dacs, dbcs);
    k_lepe<<<512, 256, 0, stream>>>(v5b, lepe_w, lepe_b, lepeb);
    k_attn_w1<<<2048, 256, 0, stream>>>(qrb, krb, v5b, dacs, vwbuf);
    k_attn_h<<<2048, 256, 0, stream>>>(qrb, krb, v5b, vwbuf, dbcs, vhb, o1b);
    k_attn_w2<<<2048, 256, 0, stream>>>(qrb, krb, vhb, o1b, dacs, lepeb, attnb);
    k_proj_ln<<<1024, 256, 0, stream>>>(attnb, x, bo, ob, n1_g, n1_b, t1b);
    k_ffn<<<1024, 256, 0, stream>>>(t1b, fw1, ffn_b1, fw2, ffn_b2, n2_g, n2_b, out);
}

// Round 11
// 290.259 us; speedup vs baseline: 1.0336x; 1.0336x over previous
//
#include <hip/hip_runtime.h>
#include <math.h>

#define HWSZ 16384

typedef __attribute__((ext_vector_type(8))) short bf16x8;
typedef __attribute__((ext_vector_type(4))) float f32x4;
typedef unsigned short u16;

union U4 { uint4 v; u16 s[8]; };
union U2 { uint2 v; u16 s[4]; };

__device__ __forceinline__ float gelu_f(float v) {
    return 0.5f * v * (1.0f + erff(v * 0.70710678118654752f));
}
__device__ __forceinline__ float splus_f(float v) {
    return (v > 20.f) ? v : log1pf(expf(v));
}
__device__ __forceinline__ u16 f2bf(float f) {
    union { float f; unsigned u; } v; v.f = f;
    unsigned r = (v.u + 0x7FFF + ((v.u >> 16) & 1)) >> 16;
    return (u16)r;
}
__device__ __forceinline__ unsigned pk2(float a, float b) {
    return (unsigned)f2bf(a) | ((unsigned)f2bf(b) << 16);
}
__device__ __forceinline__ float bf2f(u16 s) {
    union { unsigned u; float f; } v; v.u = ((unsigned)s) << 16; return v.f;
}

// ---------------- Kernel 0: weight pre-conversion to bf16 (one-time) ----------------
__global__ __launch_bounds__(256) void k_prep(
    const float* __restrict__ w1, const float* __restrict__ qw,
    const float* __restrict__ kw, const float* __restrict__ vw,
    const float* __restrict__ ow, const float* __restrict__ fw1s,
    const float* __restrict__ fw2s, u16* __restrict__ wout)
{
    int id = blockIdx.x*256 + threadIdx.x;
    float v;
    if (id < 8192) {
        v = w1[id];
    } else if (id < 20480) {
        int t = id - 8192; int m = t >> 12;
        int i = t & 4095; int o = i >> 6, c = i & 63;
        const float* src = (m==0) ? qw : ((m==1) ? kw : vw);
        v = src[c*64 + o];
        if (m == 1) v *= 0.25f;
    } else if (id < 24576) {
        int i = id - 20480; int c = i >> 6, k = i & 63;
        v = ow[k*64 + c];
    } else if (id < 40960) {
        int i = id - 24576; int o = i >> 6, k = i & 63;
        v = fw1s[k*256 + o];
    } else {
        int i = id - 40960; int jc = i >> 12; int r = i & 4095;
        int c = r >> 6, k2 = r & 63;
        v = fw2s[(jc*64 + k2)*64 + c];
    }
    wout[id] = f2bf(v);
}

// ---------------- Kernel 1: fusion gate (MFMA) -> fused bf16 [p][c] ----------------
#define FS 136
__global__ __launch_bounds__(256) void k_fuse(
    const float* __restrict__ y, const float* __restrict__ th,
    const u16* __restrict__ wfuse, const float* __restrict__ b1,
    const float* __restrict__ w2, const float* __restrict__ b2,
    u16* __restrict__ fused)
{
    __shared__ u16 Fsh[128*FS];
    __shared__ u16 Wt[64*FS];
    int tid = threadIdx.x, bid = blockIdx.x;
    int pbase = bid*128;
    int b = pbase >> 14, p0 = pbase & 16383;
    for (int vi = tid; vi < 1024; vi += 256) {
        int cp = vi >> 5;
        int p4 = (vi & 31)*4;
        int c0 = cp*2;
        float4 a = *(const float4*)&y [((size_t)(b*64+c0  ))*HWSZ + p0 + p4];
        float4 c = *(const float4*)&y [((size_t)(b*64+c0+1))*HWSZ + p0 + p4];
        *(unsigned*)&Fsh[(p4+0)*FS + c0] = pk2(a.x, c.x);
        *(unsigned*)&Fsh[(p4+1)*FS + c0] = pk2(a.y, c.y);
        *(unsigned*)&Fsh[(p4+2)*FS + c0] = pk2(a.z, c.z);
        *(unsigned*)&Fsh[(p4+3)*FS + c0] = pk2(a.w, c.w);
        float4 e = *(const float4*)&th[((size_t)(b*64+c0  ))*HWSZ + p0 + p4];
        float4 f = *(const float4*)&th[((size_t)(b*64+c0+1))*HWSZ + p0 + p4];
        *(unsigned*)&Fsh[(p4+0)*FS + 64 + c0] = pk2(e.x, f.x);
        *(unsigned*)&Fsh[(p4+1)*FS + 64 + c0] = pk2(e.y, f.y);
        *(unsigned*)&Fsh[(p4+2)*FS + 64 + c0] = pk2(e.z, f.z);
        *(unsigned*)&Fsh[(p4+3)*FS + 64 + c0] = pk2(e.w, f.w);
    }
    for (int vi = tid; vi < 1024; vi += 256) {
        int o = vi >> 4, s8 = (vi & 15)*8;
        *(uint4*)&Wt[o*FS + s8] = *(const uint4*)&wfuse[o*128 + s8];
    }
    __syncthreads();
    int lane = tid & 63, wv = tid >> 6;
    int quad = lane >> 4, lm = lane & 15;
    int M0 = wv*32;
    f32x4 z = {0.f,0.f,0.f,0.f};
    f32x4 acc[2][4];
    #pragma unroll
    for (int mt = 0; mt < 2; ++mt)
        #pragma unroll
        for (int nt = 0; nt < 4; ++nt) acc[mt][nt] = z;
    #pragma unroll
    for (int ks = 0; ks < 4; ++ks) {
        bf16x8 aF[2];
        #pragma unroll
        for (int mt = 0; mt < 2; ++mt)
            aF[mt] = *(bf16x8*)&Fsh[(M0+mt*16+lm)*FS + ks*32 + quad*8];
        #pragma unroll
        for (int nt = 0; nt < 4; ++nt) {
            bf16x8 bW = *(bf16x8*)&Wt[(nt*16+lm)*FS + ks*32 + quad*8];
            #pragma unroll
            for (int mt = 0; mt < 2; ++mt)
                acc[mt][nt] = __builtin_amdgcn_mfma_f32_16x16x32_bf16(aF[mt], bW, acc[mt][nt], 0,0,0);
        }
    }
    float b1v[4], w2av[4], w2bv[4];
    #pragma unroll
    for (int nt = 0; nt < 4; ++nt) {
        int o = nt*16 + lm;
        b1v[nt] = b1[o]; w2av[nt] = w2[o]; w2bv[nt] = w2[64+o];
    }
    float bias2a = b2[0], bias2b = b2[1];
    size_t gbase = (size_t)(b*16384 + p0);
    #pragma unroll
    for (int mt = 0; mt < 2; ++mt) {
        #pragma unroll
        for (int r = 0; r < 4; ++r) {
            int p = M0 + mt*16 + quad*4 + r;
            float l0 = 0.f, l1 = 0.f;
            #pragma unroll
            for (int nt = 0; nt < 4; ++nt) {
                float h = fmaxf(acc[mt][nt][r] + b1v[nt], 0.f);
                l0 += h * w2av[nt];
                l1 += h * w2bv[nt];
            }
            l0 += __shfl_xor(l0,1,64); l0 += __shfl_xor(l0,2,64);
            l0 += __shfl_xor(l0,4,64); l0 += __shfl_xor(l0,8,64);
            l1 += __shfl_xor(l1,1,64); l1 += __shfl_xor(l1,2,64);
            l1 += __shfl_xor(l1,4,64); l1 += __shfl_xor(l1,8,64);
            l0 += bias2a; l1 += bias2b;
            float m = fmaxf(l0, l1);
            float e0 = __expf(l0 - m), e1 = __expf(l1 - m);
            float inv = 1.f/(e0 + e1);
            float wa = e0*inv, wb = e1*inv;
            U2 yv, tv;
            yv.v = *(uint2*)&Fsh[p*FS + lm*4];
            tv.v = *(uint2*)&Fsh[p*FS + 64 + lm*4];
            unsigned o0 = pk2(bf2f(yv.s[0])*wa + bf2f(tv.s[0])*wb,
                              bf2f(yv.s[1])*wa + bf2f(tv.s[1])*wb);
            unsigned o1 = pk2(bf2f(yv.s[2])*wa + bf2f(tv.s[2])*wb,
                              bf2f(yv.s[3])*wa + bf2f(tv.s[3])*wb);
            *(uint2*)&fused[(gbase + p)*64 + lm*4] = make_uint2(o0, o1);
        }
    }
}

// ---------------- Kernel 2: QKV + RoPE + dt (MFMA, 64 pos/block) ----------------
__global__ __launch_bounds__(256) void k_qkv(
    const float* __restrict__ x, const u16* __restrict__ fused,
    const u16* __restrict__ bq, const float* __restrict__ qb,
    const u16* __restrict__ bk, const float* __restrict__ kb,
    const u16* __restrict__ bv, const float* __restrict__ vb,
    const float* __restrict__ dtw, const float* __restrict__ dtb,
    const float* __restrict__ alog,
    u16* __restrict__ qr, u16* __restrict__ kr, u16* __restrict__ v5,
    float* __restrict__ da, float* __restrict__ db)
{
    __shared__ u16 Ax[64*72];
    __shared__ u16 Af[64*72];
    __shared__ u16 Bq[64*72], Bk[64*72], Bv[64*72];
    int tid = threadIdx.x, bid = blockIdx.x;
    int pbase = bid*64;
    int b = pbase >> 14, p0 = pbase & 16383;
    for (int vi = tid; vi < 512; vi += 256) {
        int cp = vi >> 4, p4 = (vi & 15)*4;
        int c0 = cp*2;
        float4 a = *(const float4*)&x[((size_t)(b*64+c0  ))*HWSZ + p0 + p4];
        float4 c = *(const float4*)&x[((size_t)(b*64+c0+1))*HWSZ + p0 + p4];
        *(unsigned*)&Ax[(p4+0)*72 + c0] = pk2(a.x, c.x);
        *(unsigned*)&Ax[(p4+1)*72 + c0] = pk2(a.y, c.y);
        *(unsigned*)&Ax[(p4+2)*72 + c0] = pk2(a.z, c.z);
        *(unsigned*)&Ax[(p4+3)*72 + c0] = pk2(a.w, c.w);
    }
    for (int vi = tid; vi < 512; vi += 256) {
        int p = vi >> 3, seg = (vi & 7)*8;
        *(uint4*)&Af[p*72 + seg] = *(const uint4*)&fused[((size_t)(b*16384) + p0 + p)*64 + seg];
    }
    for (int vi = tid; vi < 1536; vi += 256) {
        int m = vi >> 9;
        int i = vi & 511;
        int o = i >> 3, s8 = (i & 7)*8;
        const u16* src = (m==0) ? bq : ((m==1) ? bk : bv);
        u16* dst = (m==0) ? Bq : ((m==1) ? Bk : Bv);
        *(uint4*)&dst[o*72 + s8] = *(const uint4*)&src[o*64 + s8];
    }
    __syncthreads();
    int lane = tid & 63, wv = tid >> 6;
    int quad = lane >> 4, lm = lane & 15;
    int M0 = wv*16;
    f32x4 z = {0.f,0.f,0.f,0.f};
    f32x4 accQ[4], accK[4], accV[4];
    #pragma unroll
    for (int nt = 0; nt < 4; ++nt) { accQ[nt]=z; accK[nt]=z; accV[nt]=z; }
    #pragma unroll
    for (int ks = 0; ks < 2; ++ks) {
        bf16x8 aX = *(bf16x8*)&Ax[(M0+lm)*72 + ks*32 + quad*8];
        bf16x8 aF = *(bf16x8*)&Af[(M0+lm)*72 + ks*32 + quad*8];
        #pragma unroll
        for (int nt = 0; nt < 4; ++nt) {
            bf16x8 bQ = *(bf16x8*)&Bq[(nt*16+lm)*72 + ks*32 + quad*8];
            bf16x8 bK = *(bf16x8*)&Bk[(nt*16+lm)*72 + ks*32 + quad*8];
            bf16x8 bV = *(bf16x8*)&Bv[(nt*16+lm)*72 + ks*32 + quad*8];
            accQ[nt] = __builtin_amdgcn_mfma_f32_16x16x32_bf16(aX, bQ, accQ[nt], 0,0,0);
            accK[nt] = __builtin_amdgcn_mfma_f32_16x16x32_bf16(aF, bK, accK[nt], 0,0,0);
            accV[nt] = __builtin_amdgcn_mfma_f32_16x16x32_bf16(aF, bV, accV[nt], 0,0,0);
        }
    }
    {
        float dtw_[32];
        #pragma unroll
        for (int i = 0; i < 32; ++i) dtw_[i] = dtw[i];
        int p = tid >> 2, n = tid & 3;
        U4 a, c;
        a.v = *(const uint4*)&Ax[p*72 + n*16];
        c.v = *(const uint4*)&Ax[p*72 + n*16 + 8];
        float dt0 = 0.f, dt1 = 0.f;
        #pragma unroll
        for (int d = 0; d < 8; ++d) {
            float xv = bf2f(a.s[d]);
            dt0 += xv*dtw_[2*d];
            dt1 += xv*dtw_[2*d+1];
        }
        #pragma unroll
        for (int d = 0; d < 8; ++d) {
            float xv = bf2f(c.s[d]);
            dt0 += xv*dtw_[16+2*d];
            dt1 += xv*dtw_[16+2*d+1];
        }
        float A = -expf(alog[n]);
        float bb = dtb[n];
        int P = p0 + p;
        int h = P >> 7, w = P & 127;
        da[((b*128+h)*4+n)*128 + w] = splus_f(dt0+bb)*A;
        db[((b*128+w)*4+n)*128 + h] = splus_f(dt1+bb)*A;
    }
    float qbv[4], kbv[4], vbv[4];
    #pragma unroll
    for (int nt = 0; nt < 4; ++nt) {
        qbv[nt] = qb[nt*16+lm]; kbv[nt] = kb[nt*16+lm]*0.25f; vbv[nt] = vb[nt*16+lm];
    }
    bool evn = !(lm & 1);
    float ang = exp2f(-1.89824462565f * (float)(lm >> 1));
    int bb4 = b*4;
    #pragma unroll
    for (int r = 0; r < 4; ++r) {
        int P = p0 + M0 + quad*4 + r;
        float sn_, cs_;
        sincosf((float)P * ang, &sn_, &cs_);
        #pragma unroll
        for (int nt = 0; nt < 4; ++nt) {
            float vq = accQ[nt][r] + qbv[nt];
            float pq = __shfl_xor(vq, 1, 64);
            float rq = evn ? vq*cs_ - pq*sn_ : vq*cs_ + pq*sn_;
            unsigned uq = f2bf(rq);
            unsigned upq = (unsigned)__shfl_xor((int)uq, 1, 64);
            float vk = accK[nt][r] + kbv[nt];
            float pk = __shfl_xor(vk, 1, 64);
            float rk = evn ? vk*cs_ - pk*sn_ : vk*cs_ + pk*sn_;
            unsigned uk = f2bf(rk);
            unsigned upk = (unsigned)__shfl_xor((int)uk, 1, 64);
            unsigned uv = f2bf(accV[nt][r] + vbv[nt]);
            unsigned upv = (unsigned)__shfl_xor((int)uv, 1, 64);
            if (evn) {
                size_t off = ((size_t)(bb4+nt)*HWSZ + P)*16 + lm;
                *(unsigned*)&qr[off] = (uq & 0xffff) | (upq << 16);
                *(unsigned*)&kr[off] = (uk & 0xffff) | (upk << 16);
                *(unsigned*)&v5[off] = (uv & 0xffff) | (upv << 16);
            }
        }
    }
}

// ---------------- Kernel 3: LePE depthwise 5x5 conv (v5 bf16 in, bf16 out) ----------------
#define LROW 328
__global__ __launch_bounds__(256) void k_lepe(
    const u16* __restrict__ v5, const float* __restrict__ lw,
    const float* __restrict__ lb, u16* __restrict__ lepe)
{
    __shared__ float sv[36*LROW];
    __shared__ float swt[400];
    int tid = threadIdx.x, bid = blockIdx.x;
    int tw = bid & 7, th_ = (bid >> 3) & 3, n = (bid >> 5) & 3, b = bid >> 7;
    int bn = b*4 + n;
    int h0 = th_*32, w0 = tw*16;
    for (int i = tid; i < 400; i += 256) {
        int tap = i >> 4, d = i & 15;
        swt[i] = lw[tap*64 + n*16 + d];
    }
    const u16* vb = v5 + (size_t)bn*HWSZ*16;
    for (int vi = tid; vi < 1440; vi += 256) {
        int cell = vi >> 1, half = vi & 1;
        int hh = cell/20, ww = cell - hh*20;
        int h = h0 - 2 + hh, w = w0 - 2 + ww;
        U4 val; val.v = make_uint4(0,0,0,0);
        if (h >= 0 && h < 128 && w >= 0 && w < 128)
            val.v = *(const uint4*)&vb[((size_t)(h*128+w))*16 + half*8];
        float* dst = &sv[hh*LROW + ww*16 + half*8];
        #pragma unroll
        for (int u = 0; u < 8; ++u) dst[u] = bf2f(val.s[u]);
    }
    __syncthreads();
    int df = (tid & 3)*4;
    int s  = tid >> 2;
    int ph = s >> 1;
    int pw = (s & 1)*8;
    float4 bv = *(const float4*)&lb[n*16 + df];
    float acc[8][4];
    #pragma unroll
    for (int ow = 0; ow < 8; ++ow) {
        acc[ow][0] = bv.x; acc[ow][1] = bv.y; acc[ow][2] = bv.z; acc[ow][3] = bv.w;
    }
    #pragma unroll
    for (int ky = 0; ky < 5; ++ky) {
        float wgt[5][4];
        #pragma unroll
        for (int kx = 0; kx < 5; ++kx) {
            float4 wv = *(const float4*)&swt[(ky*5+kx)*16 + df];
            wgt[kx][0]=wv.x; wgt[kx][1]=wv.y; wgt[kx][2]=wv.z; wgt[kx][3]=wv.w;
        }
        float dat[13][4];
        #pragma unroll
        for (int c = 0; c < 13; ++c) {
            float4 dv = *(const float4*)&sv[(ph+ky)*LROW + (pw+c)*16 + df];
            dat[c][0]=dv.x; dat[c][1]=dv.y; dat[c][2]=dv.z; dat[c][3]=dv.w;
        }
        #pragma unroll
        for (int ow = 0; ow < 8; ++ow)
            #pragma unroll
            for (int kx = 0; kx < 5; ++kx)
                #pragma unroll
                for (int u = 0; u < 4; ++u)
                    acc[ow][u] += dat[ow+kx][u]*wgt[kx][u];
    }
    u16* ob = lepe + ((size_t)bn*HWSZ + (size_t)(h0+ph)*128 + w0+pw)*16 + df;
    #pragma unroll
    for (int ow = 0; ow < 8; ++ow)
        *(uint2*)&ob[ow*16] = make_uint2(pk2(acc[ow][0],acc[ow][1]), pk2(acc[ow][2],acc[ow][3]));
}

// ---------------- Kernel 4: row attention pass 1 -> v_w ----------------
// Q/K fragments loaded direct from global (no LDS staging; quad>=2 holds K-pad zeros).
__global__ __launch_bounds__(256) void k_attn_w1(
    const u16* __restrict__ qr, const u16* __restrict__ kr,
    const u16* __restrict__ v5, const float* __restrict__ dacs,
    u16* __restrict__ vwb)
{
    __shared__ u16 Vt[16*136], Ps[128*136];
    __shared__ float csr[128];
    int tid = threadIdx.x, bid = blockIdx.x;
    int h = bid & 127, n = (bid >> 7) & 3, b = bid >> 9;
    size_t rowoff = ((size_t)((b*4+n)*128 + h)) * 2048;
    {   // V^T
        int jp = tid >> 2, q4 = tid & 3;
        U2 a, c;
        a.v = *(const uint2*)&v5[rowoff + (2*jp)*16 + q4*4];
        c.v = *(const uint2*)&v5[rowoff + (2*jp+1)*16 + q4*4];
        #pragma unroll
        for (int u = 0; u < 4; ++u)
            *(unsigned*)&Vt[(q4*4+u)*136 + 2*jp] = (unsigned)a.s[u] | ((unsigned)c.s[u] << 16);
    }
    if (tid < 128) csr[tid] = dacs[((b*128+h)*4+n)*128 + tid];
    __syncthreads();
    if (tid < 64) {
        float2 e = *(float2*)&csr[tid*2];
        float s = e.x + e.y;
        #pragma unroll
        for (int d = 1; d < 64; d <<= 1) {
            float t = __shfl_up(s, d, 64);
            if (tid >= d) s += t;
        }
        csr[tid*2]   = s - e.y;
        csr[tid*2+1] = s;
    }
    __syncthreads();
    int lane = tid & 63, wv = tid >> 6;
    int quad = lane >> 4, lm = lane & 15;
    int r0 = wv*32, r1 = wv*32 + 16;
    bf16x8 z8 = {0,0,0,0,0,0,0,0};
    bf16x8 aQ0 = z8, aQ1 = z8;
    if (quad < 2) {
        aQ0 = *(const bf16x8*)&qr[rowoff + (size_t)(r0+lm)*16 + quad*8];
        aQ1 = *(const bf16x8*)&qr[rowoff + (size_t)(r1+lm)*16 + quad*8];
    }
    float csj[8], csi0[4], csi1[4];
    #pragma unroll
    for (int jt = 0; jt < 8; ++jt) csj[jt] = csr[jt*16+lm];
    #pragma unroll
    for (int r = 0; r < 4; ++r) { csi0[r] = csr[r0+quad*4+r]; csi1[r] = csr[r1+quad*4+r]; }
    float ls0[4]={0,0,0,0}, ls1[4]={0,0,0,0};
    f32x4 z = {0.f,0.f,0.f,0.f};
    #pragma unroll
    for (int jt = 0; jt < 8; ++jt) {
        bf16x8 bK = z8;
        if (quad < 2) bK = *(const bf16x8*)&kr[rowoff + (size_t)(jt*16+lm)*16 + quad*8];
        f32x4 s0 = __builtin_amdgcn_mfma_f32_16x16x32_bf16(aQ0, bK, z, 0,0,0);
        f32x4 s1 = __builtin_amdgcn_mfma_f32_16x16x32_bf16(aQ1, bK, z, 0,0,0);
        #pragma unroll
        for (int r = 0; r < 4; ++r) {
            float e0 = __expf(s0[r] - fabsf(csi0[r]-csj[jt])); ls0[r] += e0;
            float e1 = __expf(s1[r] - fabsf(csi1[r]-csj[jt])); ls1[r] += e1;
            Ps[(r0+quad*4+r)*136 + jt*16+lm] = f2bf(e0);
            Ps[(r1+quad*4+r)*136 + jt*16+lm] = f2bf(e1);
        }
    }
    float inv0[4], inv1[4];
    #pragma unroll
    for (int r = 0; r < 4; ++r) {
        #pragma unroll
        for (int m = 1; m < 16; m <<= 1) {
            ls0[r] += __shfl_xor(ls0[r], m, 64);
            ls1[r] += __shfl_xor(ls1[r], m, 64);
        }
        inv0[r] = 1.f/ls0[r]; inv1[r] = 1.f/ls1[r];
    }
    __syncthreads();
    f32x4 acc0 = z, acc1 = z;
    #pragma unroll
    for (int c = 0; c < 4; ++c) {
        bf16x8 bV  = *(bf16x8*)&Vt[lm*136 + c*32 + quad*8];
        bf16x8 aP0 = *(bf16x8*)&Ps[(r0+lm)*136 + c*32 + quad*8];
        bf16x8 aP1 = *(bf16x8*)&Ps[(r1+lm)*136 + c*32 + quad*8];
        acc0 = __builtin_amdgcn_mfma_f32_16x16x32_bf16(aP0, bV, acc0, 0,0,0);
        acc1 = __builtin_amdgcn_mfma_f32_16x16x32_bf16(aP1, bV, acc1, 0,0,0);
    }
    bool evn = !(lm & 1);
    #pragma unroll
    for (int r = 0; r < 4; ++r) {
        int i0 = r0+quad*4+r, i1 = r1+quad*4+r;
        unsigned u0 = f2bf(acc0[r]*inv0[r]);
        unsigned u1 = f2bf(acc1[r]*inv1[r]);
        unsigned up0 = (unsigned)__shfl_xor((int)u0, 1, 64);
        unsigned up1 = (unsigned)__shfl_xor((int)u1, 1, 64);
        if (evn) {
            *(unsigned*)&vwb[rowoff + (size_t)i0*16 + lm] = (u0 & 0xffff) | (up0 << 16);
            *(unsigned*)&vwb[rowoff + (size_t)i1*16 + lm] = (u1 & 0xffff) | (up1 << 16);
        }
    }
}

// ---------------- Kernel 5: column attention -> v_h, out1 ----------------
__global__ __launch_bounds__(256) void k_attn_h(
    const u16* __restrict__ qr, const u16* __restrict__ kr,
    const u16* __restrict__ v5, const u16* __restrict__ vwb,
    const float* __restrict__ dbcs,
    u16* __restrict__ vhb, u16* __restrict__ o1b)
{
    __shared__ u16 Vt[16*136], Wt[16*136], Ps[128*136];
    __shared__ float csr[128];
    int tid = threadIdx.x, bid = blockIdx.x;
    int w = bid & 127, n = (bid >> 7) & 3, b = bid >> 9;
    int bn = b*4 + n;
    size_t base = ((size_t)bn*16384 + w)*16;
    {
        int jp = tid >> 2, q4 = tid & 3;
        U2 a, c, e, f;
        a.v = *(const uint2*)&v5 [base + (size_t)(2*jp)*2048 + q4*4];
        c.v = *(const uint2*)&v5 [base + (size_t)(2*jp+1)*2048 + q4*4];
        e.v = *(const uint2*)&vwb[base + (size_t)(2*jp)*2048 + q4*4];
        f.v = *(const uint2*)&vwb[base + (size_t)(2*jp+1)*2048 + q4*4];
        #pragma unroll
        for (int u = 0; u < 4; ++u) {
            *(unsigned*)&Vt[(q4*4+u)*136 + 2*jp] = (unsigned)a.s[u] | ((unsigned)c.s[u] << 16);
            *(unsigned*)&Wt[(q4*4+u)*136 + 2*jp] = (unsigned)e.s[u] | ((unsigned)f.s[u] << 16);
        }
    }
    if (tid < 128) csr[tid] = dbcs[((b*128+w)*4+n)*128 + tid];
    __syncthreads();
    if (tid < 64) {
        float2 e = *(float2*)&csr[tid*2];
        float s = e.x + e.y;
        #pragma unroll
        for (int d = 1; d < 64; d <<= 1) {
            float t = __shfl_up(s, d, 64);
            if (tid >= d) s += t;
        }
        csr[tid*2]   = s - e.y;
        csr[tid*2+1] = s;
    }
    __syncthreads();
    int lane = tid & 63, wv = tid >> 6;
    int quad = lane >> 4, lm = lane & 15;
    int r0 = wv*32, r1 = wv*32 + 16;
    bf16x8 z8 = {0,0,0,0,0,0,0,0};
    bf16x8 aQ0 = z8, aQ1 = z8;
    if (quad < 2) {
        aQ0 = *(const bf16x8*)&qr[base + (size_t)(r0+lm)*2048 + quad*8];
        aQ1 = *(const bf16x8*)&qr[base + (size_t)(r1+lm)*2048 + quad*8];
    }
    float csj[8], csi0[4], csi1[4];
    #pragma unroll
    for (int jt = 0; jt < 8; ++jt) csj[jt] = csr[jt*16+lm];
    #pragma unroll
    for (int r = 0; r < 4; ++r) { csi0[r] = csr[r0+quad*4+r]; csi1[r] = csr[r1+quad*4+r]; }
    float ls0[4]={0,0,0,0}, ls1[4]={0,0,0,0};
    f32x4 z = {0.f,0.f,0.f,0.f};
    #pragma unroll
    for (int jt = 0; jt < 8; ++jt) {
        bf16x8 bK = z8;
        if (quad < 2) bK = *(const bf16x8*)&kr[base + (size_t)(jt*16+lm)*2048 + quad*8];
        f32x4 s0 = __builtin_amdgcn_mfma_f32_16x16x32_bf16(aQ0, bK, z, 0,0,0);
        f32x4 s1 = __builtin_amdgcn_mfma_f32_16x16x32_bf16(aQ1, bK, z, 0,0,0);
        #pragma unroll
        for (int r = 0; r < 4; ++r) {
            float e0 = __expf(s0[r] - fabsf(csi0[r]-csj[jt])); ls0[r] += e0;
            float e1 = __expf(s1[r] - fabsf(csi1[r]-csj[jt])); ls1[r] += e1;
            Ps[(r0+quad*4+r)*136 + jt*16+lm] = f2bf(e0);
            Ps[(r1+quad*4+r)*136 + jt*16+lm] = f2bf(e1);
        }
    }
    float inv0[4], inv1[4];
    #pragma unroll
    for (int r = 0; r < 4; ++r) {
        #pragma unroll
        for (int m = 1; m < 16; m <<= 1) {
            ls0[r] += __shfl_xor(ls0[r], m, 64);
            ls1[r] += __shfl_xor(ls1[r], m, 64);
        }
        inv0[r] = 1.f/ls0[r]; inv1[r] = 1.f/ls1[r];
    }
    __syncthreads();
    f32x4 aV0 = z, aV1 = z, aW0 = z, aW1 = z;
    #pragma unroll
    for (int c = 0; c < 4; ++c) {
        bf16x8 bV  = *(bf16x8*)&Vt[lm*136 + c*32 + quad*8];
        bf16x8 bW  = *(bf16x8*)&Wt[lm*136 + c*32 + quad*8];
        bf16x8 aP0 = *(bf16x8*)&Ps[(r0+lm)*136 + c*32 + quad*8];
        bf16x8 aP1 = *(bf16x8*)&Ps[(r1+lm)*136 + c*32 + quad*8];
        aV0 = __builtin_amdgcn_mfma_f32_16x16x32_bf16(aP0, bV, aV0, 0,0,0);
        aV1 = __builtin_amdgcn_mfma_f32_16x16x32_bf16(aP1, bV, aV1, 0,0,0);
        aW0 = __builtin_amdgcn_mfma_f32_16x16x32_bf16(aP0, bW, aW0, 0,0,0);
        aW1 = __builtin_amdgcn_mfma_f32_16x16x32_bf16(aP1, bW, aW1, 0,0,0);
    }
    size_t obase = ((size_t)bn*16384 + (size_t)w*128)*16;   // [w][h][d]
    bool evn = !(lm & 1);
    #pragma unroll
    for (int r = 0; r < 4; ++r) {
        int i0 = r0+quad*4+r, i1 = r1+quad*4+r;
        float v0 = inv0[r], v1 = inv1[r];
        unsigned a0 = f2bf(aV0[r]*v0), a1 = f2bf(aV1[r]*v1);
        unsigned b0 = f2bf(aW0[r]*v0), b1 = f2bf(aW1[r]*v1);
        unsigned ap0 = (unsigned)__shfl_xor((int)a0,1,64), ap1 = (unsigned)__shfl_xor((int)a1,1,64);
        unsigned bp0 = (unsigned)__shfl_xor((int)b0,1,64), bp1 = (unsigned)__shfl_xor((int)b1,1,64);
        if (evn) {
            *(unsigned*)&vhb[obase + (size_t)i0*16 + lm] = (a0 & 0xffff) | (ap0 << 16);
            *(unsigned*)&vhb[obase + (size_t)i1*16 + lm] = (a1 & 0xffff) | (ap1 << 16);
            *(unsigned*)&o1b[obase + (size_t)i0*16 + lm] = (b0 & 0xffff) | (bp0 << 16);
            *(unsigned*)&o1b[obase + (size_t)i1*16 + lm] = (b1 & 0xffff) | (bp1 << 16);
        }
    }
}

// ---------------- Kernel 6: row attention pass 2 -> out2, combine + lepe ----------------
__global__ __launch_bounds__(256) void k_attn_w2(
    const u16* __restrict__ qr, const u16* __restrict__ kr,
    const u16* __restrict__ vhb, const u16* __restrict__ o1b,
    const float* __restrict__ dacs, const u16* __restrict__ lepe,
    u16* __restrict__ attn)
{
    __shared__ u16 Vt[16*136], Ps[128*136];
    __shared__ float csr[128];
    int tid = threadIdx.x, bid = blockIdx.x;
    int h = bid & 127, n = (bid >> 7) & 3, b = bid >> 9;
    int bn = b*4 + n;
    size_t rowoff = ((size_t)(bn*128 + h)) * 2048;
    size_t vbase  = (size_t)bn*262144 + (size_t)h*16;
    {
        int jp = tid >> 2, q4 = tid & 3;
        U2 a, c;
        a.v = *(const uint2*)&vhb[vbase + (size_t)(2*jp)*2048 + q4*4];
        c.v = *(const uint2*)&vhb[vbase + (size_t)(2*jp+1)*2048 + q4*4];
        #pragma unroll
        for (int u = 0; u < 4; ++u)
            *(unsigned*)&Vt[(q4*4+u)*136 + 2*jp] = (unsigned)a.s[u] | ((unsigned)c.s[u] << 16);
    }
    if (tid < 128) csr[tid] = dacs[((b*128+h)*4+n)*128 + tid];
    __syncthreads();
    if (tid < 64) {
        float2 e = *(float2*)&csr[tid*2];
        float s = e.x + e.y;
        #pragma unroll
        for (int d = 1; d < 64; d <<= 1) {
            float t = __shfl_up(s, d, 64);
            if (tid >= d) s += t;
        }
        csr[tid*2]   = s - e.y;
        csr[tid*2+1] = s;
    }
    __syncthreads();
    int lane = tid & 63, wv = tid >> 6;
    int quad = lane >> 4, lm = lane & 15;
    int r0 = wv*32, r1 = wv*32 + 16;
    bf16x8 z8 = {0,0,0,0,0,0,0,0};
    bf16x8 aQ0 = z8, aQ1 = z8;
    if (quad < 2) {
        aQ0 = *(const bf16x8*)&qr[rowoff + (size_t)(r0+lm)*16 + quad*8];
        aQ1 = *(const bf16x8*)&qr[rowoff + (size_t)(r1+lm)*16 + quad*8];
    }
    float csj[8], csi0[4], csi1[4];
    #pragma unroll
    for (int jt = 0; jt < 8; ++jt) csj[jt] = csr[jt*16+lm];
    #pragma unroll
    for (int r = 0; r < 4; ++r) { csi0[r] = csr[r0+quad*4+r]; csi1[r] = csr[r1+quad*4+r]; }
    float ls0[4]={0,0,0,0}, ls1[4]={0,0,0,0};
    f32x4 z = {0.f,0.f,0.f,0.f};
    #pragma unroll
    for (int jt = 0; jt < 8; ++jt) {
        bf16x8 bK = z8;
        if (quad < 2) bK = *(const bf16x8*)&kr[rowoff + (size_t)(jt*16+lm)*16 + quad*8];
        f32x4 s0 = __builtin_amdgcn_mfma_f32_16x16x32_bf16(aQ0, bK, z, 0,0,0);
        f32x4 s1 = __builtin_amdgcn_mfma_f32_16x16x32_bf16(aQ1, bK, z, 0,0,0);
        #pragma unroll
        for (int r = 0; r < 4; ++r) {
            float e0 = __expf(s0[r] - fabsf(csi0[r]-csj[jt])); ls0[r] += e0;
            float e1 = __expf(s1[r] - fabsf(csi1[r]-csj[jt])); ls1[r] += e1;
            Ps[(r0+quad*4+r)*136 + jt*16+lm] = f2bf(e0);
            Ps[(r1+quad*4+r)*136 + jt*16+lm] = f2bf(e1);
        }
    }
    float inv0[4], inv1[4];
    #pragma unroll
    for (int r = 0; r < 4; ++r) {
        #pragma unroll
        for (int m = 1; m < 16; m <<= 1) {
            ls0[r] += __shfl_xor(ls0[r], m, 64);
            ls1[r] += __shfl_xor(ls1[r], m, 64);
        }
        inv0[r] = 1.f/ls0[r]; inv1[r] = 1.f/ls1[r];
    }
    __syncthreads();
    f32x4 acc0 = z, acc1 = z;
    #pragma unroll
    for (int c = 0; c < 4; ++c) {
        bf16x8 bV  = *(bf16x8*)&Vt[lm*136 + c*32 + quad*8];
        bf16x8 aP0 = *(bf16x8*)&Ps[(r0+lm)*136 + c*32 + quad*8];
        bf16x8 aP1 = *(bf16x8*)&Ps[(r1+lm)*136 + c*32 + quad*8];
        acc0 = __builtin_amdgcn_mfma_f32_16x16x32_bf16(aP0, bV, acc0, 0,0,0);
        acc1 = __builtin_amdgcn_mfma_f32_16x16x32_bf16(aP1, bV, acc1, 0,0,0);
    }
    size_t lpb = (size_t)bn*262144 + (size_t)h*2048;
    size_t oab = (size_t)b*1048576 + (size_t)h*8192 + n*16;
    bool evn = !(lm & 1);
    #pragma unroll
    for (int r = 0; r < 4; ++r) {
        int i0 = r0+quad*4+r, i1 = r1+quad*4+r;
        float o2a = acc0[r]*inv0[r];
        float o2b = acc1[r]*inv1[r];
        float o1a = bf2f(o1b[vbase + (size_t)i0*2048 + lm]);
        float o1c = bf2f(o1b[vbase + (size_t)i1*2048 + lm]);
        float la  = bf2f(lepe[lpb + (size_t)i0*16 + lm]);
        float lc  = bf2f(lepe[lpb + (size_t)i1*16 + lm]);
        unsigned ua = f2bf(0.5f*(o1a + o2a) + la);
        unsigned uc = f2bf(0.5f*(o1c + o2b) + lc);
        unsigned upa = (unsigned)__shfl_xor((int)ua,1,64);
        unsigned upc = (unsigned)__shfl_xor((int)uc,1,64);
        if (evn) {
            *(unsigned*)&attn[oab + (size_t)i0*64 + lm] = (ua & 0xffff) | (upa << 16);
            *(unsigned*)&attn[oab + (size_t)i1*64 + lm] = (uc & 0xffff) | (upc << 16);
        }
    }
}

// ---------------- Kernel 7: out-proj + residual + LN1 (MFMA, 64 pos/block) ----------------
__global__ __launch_bounds__(256) void k_proj_ln(
    const u16* __restrict__ attn, const float* __restrict__ x,
    const u16* __restrict__ bo, const float* __restrict__ ob,
    const float* __restrict__ g1, const float* __restrict__ b1,
    u16* __restrict__ t1)
{
    __shared__ u16 As[64*72];
    __shared__ u16 Bs[64*72];
    __shared__ float XT[64*68];
    int tid = threadIdx.x, bid = blockIdx.x;
    int pbase = bid*64;
    int b = pbase >> 14, p0 = pbase & 16383;
    for (int vi = tid; vi < 512; vi += 256) {
        int p = vi >> 3, s8 = (vi & 7)*8;
        *(uint4*)&As[p*72 + s8] = *(const uint4*)&attn[((size_t)(pbase+p))*64 + s8];
    }
    for (int vi = tid; vi < 512; vi += 256) {
        int c = vi >> 3, s8 = (vi & 7)*8;
        *(uint4*)&Bs[c*72 + s8] = *(const uint4*)&bo[c*64 + s8];
    }
    for (int vi = tid; vi < 1024; vi += 256) {
        int c = vi >> 4, p4 = (vi & 15)*4;
        *(float4*)&XT[c*68 + p4] = *(const float4*)&x[((size_t)(b*64+c))*HWSZ + p0 + p4];
    }
    __syncthreads();
    int lane = tid & 63, wv = tid >> 6;
    int quad = lane >> 4, lm = lane & 15;
    int M0 = wv*16;
    float xv[4][4], obv[4], g1v[4], b1v[4];
    #pragma unroll
    for (int nt = 0; nt < 4; ++nt) {
        int c = nt*16 + lm;
        obv[nt] = ob[c]; g1v[nt] = g1[c]; b1v[nt] = b1[c];
        #pragma unroll
        for (int r = 0; r < 4; ++r)
            xv[nt][r] = XT[c*68 + M0 + quad*4 + r];
    }
    f32x4 z = {0.f,0.f,0.f,0.f};
    f32x4 acc[4];
    #pragma unroll
    for (int nt = 0; nt < 4; ++nt) acc[nt] = z;
    #pragma unroll
    for (int ks = 0; ks < 2; ++ks) {
        bf16x8 aF = *(bf16x8*)&As[(M0+lm)*72 + ks*32 + quad*8];
        #pragma unroll
        for (int nt = 0; nt < 4; ++nt) {
            bf16x8 bF = *(bf16x8*)&Bs[(nt*16+lm)*72 + ks*32 + quad*8];
            acc[nt] = __builtin_amdgcn_mfma_f32_16x16x32_bf16(aF, bF, acc[nt], 0,0,0);
        }
    }
    float val[4][4], res[4][4];
    #pragma unroll
    for (int r = 0; r < 4; ++r) {
        float s = 0.f;
        #pragma unroll
        for (int nt = 0; nt < 4; ++nt) {
            val[nt][r] = acc[nt][r] + obv[nt] + xv[nt][r];
            s += val[nt][r];
        }
        s += __shfl_xor(s, 1, 64); s += __shfl_xor(s, 2, 64);
        s += __shfl_xor(s, 4, 64); s += __shfl_xor(s, 8, 64);
        float mean = s*(1.f/64.f);
        float vv = 0.f;
        #pragma unroll
        for (int nt = 0; nt < 4; ++nt) {
            float d = val[nt][r] - mean;
            vv += d*d;
        }
        vv += __shfl_xor(vv, 1, 64); vv += __shfl_xor(vv, 2, 64);
        vv += __shfl_xor(vv, 4, 64); vv += __shfl_xor(vv, 8, 64);
        float rs = rsqrtf(vv*(1.f/64.f) + 1e-5f);
        #pragma unroll
        for (int nt = 0; nt < 4; ++nt)
            res[nt][r] = (val[nt][r] - mean)*rs*g1v[nt] + b1v[nt];
    }
    __syncthreads();
    float* outT = XT;   // [p][68]
    #pragma unroll
    for (int r = 0; r < 4; ++r)
        #pragma unroll
        for (int nt = 0; nt < 4; ++nt)
            outT[(M0+quad*4+r)*68 + nt*16 + lm] = res[nt][r];
    __syncthreads();
    for (int vi = tid; vi < 512; vi += 256) {
        int p = vi >> 3, s8 = (vi & 7)*8;
        float4 f0 = *(const float4*)&outT[p*68 + s8];
        float4 f1 = *(const float4*)&outT[p*68 + s8 + 4];
        uint4 o = make_uint4(pk2(f0.x,f0.y), pk2(f0.z,f0.w), pk2(f1.x,f1.y), pk2(f1.z,f1.w));
        *(uint4*)&t1[((size_t)(pbase+p))*64 + s8] = o;
    }
}

// ---------------- Kernel 8: fused FFN (MFMA, 64 pos/block) + residual + LN2 + transpose ----------------
__global__ __launch_bounds__(256) void k_ffn(
    const u16* __restrict__ t1, const u16* __restrict__ fw1,
    const float* __restrict__ b1f, const u16* __restrict__ fw2,
    const float* __restrict__ b2f, const float* __restrict__ g2,
    const float* __restrict__ bb2, float* __restrict__ outp)
{
    __shared__ u16 SL[18432];
    __shared__ float sb1[256];
    __shared__ float sb2[64], sg[64], sbb[64];
    u16* At1 = SL;
    u16* W1b = SL + 4608;
    u16* W2b = SL + 9216;
    u16* Hid = SL + 13824;
    int tid = threadIdx.x, bid = blockIdx.x;
    int pbase = bid*64;
    int b = pbase >> 14, p0 = pbase & 16383;
    for (int vi = tid; vi < 512; vi += 256) {
        int p = vi >> 3, s8 = (vi & 7)*8;
        *(uint4*)&At1[p*72 + s8] = *(const uint4*)&t1[((size_t)(pbase+p))*64 + s8];
    }
    if (tid < 256) sb1[tid] = b1f[tid];
    if (tid < 64) { sb2[tid] = b2f[tid]; sg[tid] = g2[tid]; sbb[tid] = bb2[tid]; }
    int lane = tid & 63, wv = tid >> 6;
    int quad = lane >> 4, lm = lane & 15;
    int M0 = wv*16;
    f32x4 z = {0.f,0.f,0.f,0.f};
    f32x4 acc2[4];
    #pragma unroll
    for (int nt = 0; nt < 4; ++nt) acc2[nt] = z;
    for (int jc = 0; jc < 4; ++jc) {
        __syncthreads();
        for (int vi = tid; vi < 1024; vi += 256) {
            int m = vi >> 9, i = vi & 511;
            int o = i >> 3, s8 = (i & 7)*8;
            if (m == 0) *(uint4*)&W1b[o*72 + s8] = *(const uint4*)&fw1[(jc*64+o)*64 + s8];
            else        *(uint4*)&W2b[o*72 + s8] = *(const uint4*)&fw2[jc*4096 + o*64 + s8];
        }
        __syncthreads();
        f32x4 h[4];
        #pragma unroll
        for (int nt = 0; nt < 4; ++nt) h[nt] = z;
        #pragma unroll
        for (int ks = 0; ks < 2; ++ks) {
            bf16x8 aF = *(bf16x8*)&At1[(M0+lm)*72 + ks*32 + quad*8];
            #pragma unroll
            for (int nt = 0; nt < 4; ++nt) {
                bf16x8 bF = *(bf16x8*)&W1b[(nt*16+lm)*72 + ks*32 + quad*8];
                h[nt] = __builtin_amdgcn_mfma_f32_16x16x32_bf16(aF, bF, h[nt], 0,0,0);
            }
        }
        #pragma unroll
        for (int nt = 0; nt < 4; ++nt) {
            float bb = sb1[jc*64 + nt*16 + lm];
            #pragma unroll
            for (int r = 0; r < 4; ++r) {
                float hv = gelu_f(h[nt][r] + bb);
                unsigned u = (unsigned)f2bf(hv);
                unsigned up = (unsigned)__shfl_xor((int)u, 1, 64);
                if (!(lm & 1))
                    *(unsigned*)&Hid[(M0+quad*4+r)*72 + nt*16 + lm] = (u & 0xffff) | (up << 16);
            }
        }
        #pragma unroll
        for (int ks = 0; ks < 2; ++ks) {
            bf16x8 aH = *(bf16x8*)&Hid[(M0+lm)*72 + ks*32 + quad*8];
            #pragma unroll
            for (int nt = 0; nt < 4; ++nt) {
                bf16x8 bF = *(bf16x8*)&W2b[(nt*16+lm)*72 + ks*32 + quad*8];
                acc2[nt] = __builtin_amdgcn_mfma_f32_16x16x32_bf16(aH, bF, acc2[nt], 0,0,0);
            }
        }
    }
    float val[4][4], res[4][4];
    float sb2v[4], sgv[4], sbbv[4];
    #pragma unroll
    for (int nt = 0; nt < 4; ++nt) {
        int c = nt*16 + lm;
        sb2v[nt] = sb2[c]; sgv[nt] = sg[c]; sbbv[nt] = sbb[c];
    }
    #pragma unroll
    for (int r = 0; r < 4; ++r) {
        int pos = M0 + quad*4 + r;
        float s = 0.f;
        #pragma unroll
        for (int nt = 0; nt < 4; ++nt) {
            float tv = bf2f(At1[pos*72 + nt*16 + lm]);
            val[nt][r] = acc2[nt][r] + sb2v[nt] + tv;
            s += val[nt][r];
        }
        s += __shfl_xor(s, 1, 64); s += __shfl_xor(s, 2, 64);
        s += __shfl_xor(s, 4, 64); s += __shfl_xor(s, 8, 64);
        float mean = s*(1.f/64.f);
        float vv = 0.f;
        #pragma unroll
        for (int nt = 0; nt < 4; ++nt) {
            float d = val[nt][r] - mean;
            vv += d*d;
        }
        vv += __shfl_xor(vv, 1, 64); vv += __shfl_xor(vv, 2, 64);
        vv += __shfl_xor(vv, 4, 64); vv += __shfl_xor(vv, 8, 64);
        float rs = rsqrtf(vv*(1.f/64.f) + 1e-5f);
        #pragma unroll
        for (int nt = 0; nt < 4; ++nt)
            res[nt][r] = (val[nt][r] - mean)*rs*sgv[nt] + sbbv[nt];
    }
    __syncthreads();
    float* outT = (float*)SL;   // [c][68]
    #pragma unroll
    for (int r = 0; r < 4; ++r)
        #pragma unroll
        for (int nt = 0; nt < 4; ++nt)
            outT[(nt*16+lm)*68 + M0 + quad*4 + r] = res[nt][r];
    __syncthreads();
    for (int vi = tid; vi < 1024; vi += 256) {
        int c = vi >> 4, p4 = (vi & 15)*4;
        *(float4*)&outp[((size_t)(b*64+c))*HWSZ + p0 + p4] = *(const float4*)&outT[c*68 + p4];
    }
}

extern "C" void kernel_launch(void* const* d_in, const int* in_sizes, int n_in,
                              void* d_out, int out_size, void* d_ws, size_t ws_size,
                              hipStream_t stream) {
    const float* x      = (const float*)d_in[0];
    const float* y      = (const float*)d_in[1];
    const float* th     = (const float*)d_in[2];
    const float* dw1_w  = (const float*)d_in[3];
    const float* dw1_b  = (const float*)d_in[4];
    const float* dw2_w  = (const float*)d_in[5];
    const float* dw2_b  = (const float*)d_in[6];
    const float* qw     = (const float*)d_in[7];
    const float* qb     = (const float*)d_in[8];
    const float* kw     = (const float*)d_in[9];
    const float* kb     = (const float*)d_in[10];
    const float* vw     = (const float*)d_in[11];
    const float* vb     = (const float*)d_in[12];
    const float* lepe_w = (const float*)d_in[13];
    const float* lepe_b = (const float*)d_in[14];
    const float* dt_w   = (const float*)d_in[15];
    const float* dt_bias= (const float*)d_in[16];
    const float* A_log  = (const float*)d_in[17];
    const float* ow     = (const float*)d_in[18];
    const float* ob     = (const float*)d_in[19];
    const float* n1_g   = (const float*)d_in[20];
    const float* n1_b   = (const float*)d_in[21];
    const float* ffn_w1 = (const float*)d_in[22];
    const float* ffn_b1 = (const float*)d_in[23];
    const float* ffn_w2 = (const float*)d_in[24];
    const float* ffn_b2 = (const float*)d_in[25];
    const float* n2_g   = (const float*)d_in[26];
    const float* n2_b   = (const float*)d_in[27];
    float* out = (float*)d_out;

    const size_t SZ = 4194304;
    float* ws    = (float*)d_ws;
    u16* fused = (u16*)(ws + 0*SZ);    // reused as v_w (vwb) after attn_w1
    u16* qrb   = (u16*)(ws + 1*SZ);
    u16* krb   = (u16*)(ws + 2*SZ);
    u16* v5b   = (u16*)(ws + 3*SZ);
    u16* lepeb = (u16*)(ws + 4*SZ);
    u16* vhb   = (u16*)(ws + 5*SZ);
    u16* o1b   = (u16*)(ws + 6*SZ);
    u16* attnb = (u16*)(ws + 7*SZ);
    u16* t1b   = (u16*)(ws + 8*SZ);
    float* dacs  = ws + 9*SZ;
    float* dbcs  = ws + 9*SZ + 262144;
    u16* wall  = (u16*)(ws + 9*SZ + 524288);
    u16* wfuse = wall;
    u16* bq    = wall + 8192;
    u16* bk    = wall + 12288;
    u16* bv    = wall + 16384;
    u16* bo    = wall + 20480;
    u16* fw1   = wall + 24576;
    u16* fw2   = wall + 40960;

    k_prep<<<224, 256, 0, stream>>>(dw1_w, qw, kw, vw, ow, ffn_w1, ffn_w2, wall);
    k_fuse<<<512, 256, 0, stream>>>(y, th, wfuse, dw1_b, dw2_w, dw2_b, fused);
    k_qkv<<<1024, 256, 0, stream>>>(x, fused, bq, qb, bk, kb, bv, vb,
                                    dt_w, dt_bias, A_log, qrb, krb, v5b, dacs, dbcs);
    k_lepe<<<512, 256, 0, stream>>>(v5b, lepe_w, lepe_b, lepeb);
    k_attn_w1<<<2048, 256, 0, stream>>>(qrb, krb, v5b, dacs, fused);
    k_attn_h<<<2048, 256, 0, stream>>>(qrb, krb, v5b, fused, dbcs, vhb, o1b);
    k_attn_w2<<<2048, 256, 0, stream>>>(qrb, krb, vhb, o1b, dacs, lepeb, attnb);
    k_proj_ln<<<1024, 256, 0, stream>>>(attnb, x, bo, ob, n1_g, n1_b, t1b);
    k_ffn<<<1024, 256, 0, stream>>>(t1b, fw1, ffn_b1, fw2, ffn_b2, n2_g, n2_b, out);
}